// Round 1
// baseline (558.046 us; speedup 1.0000x reference)
//
#include <hip/hip_runtime.h>
#include <hip/hip_bf16.h>
#include <stdint.h>

#define B_ 2
#define S_ 1024
#define D_ 2048
#define H_ 16
#define F_ 8192
#define DH_ 128
#define M_ 2048  // B*S

typedef unsigned short u16;
typedef __attribute__((ext_vector_type(8))) short short8;
typedef __attribute__((ext_vector_type(4))) float f32x4;
typedef __attribute__((ext_vector_type(2))) float f32x2;
typedef __attribute__((ext_vector_type(2))) unsigned short u16x2;

__device__ __forceinline__ u16 f2bf(float f) {
  union { float f; uint32_t u; } c; c.f = f;
  uint32_t r = c.u + 0x7FFFu + ((c.u >> 16) & 1u);
  return (u16)(r >> 16);
}

__device__ __forceinline__ void gload16(const void* g, void* l) {
  __builtin_amdgcn_global_load_lds((const __attribute__((address_space(1))) void*)g,
                                   (__attribute__((address_space(3))) void*)l, 16, 0, 0);
}

__device__ __forceinline__ float clipa(float a) {
  return fminf(0.2f, fmaxf(-0.2f, a));
}

__device__ __forceinline__ float gelu_f(float x) {
  float z = 0.7978845608028654f * (x + 0.044715f * x * x * x);
  z = fminf(10.f, fmaxf(-10.f, z));
  float e = __expf(2.f * z);
  return 0.5f * x * (1.f + (e - 1.f) / (e + 1.f));
}

// ---------------- f32 -> bf16 vector convert ----------------
__global__ __launch_bounds__(256) void k_cvt(const float* __restrict__ s,
                                             u16* __restrict__ d, int n8) {
  int i = blockIdx.x * 256 + threadIdx.x;
  if (i >= n8) return;
  f32x4 a = *(const f32x4*)(s + (size_t)i * 8);
  f32x4 b = *(const f32x4*)(s + (size_t)i * 8 + 4);
  short8 o;
  o[0] = (short)f2bf(a[0]); o[1] = (short)f2bf(a[1]);
  o[2] = (short)f2bf(a[2]); o[3] = (short)f2bf(a[3]);
  o[4] = (short)f2bf(b[0]); o[5] = (short)f2bf(b[1]);
  o[6] = (short)f2bf(b[2]); o[7] = (short)f2bf(b[3]);
  *(short8*)(d + (size_t)i * 8) = o;
}

// ---------------- CenterNorm: y = g*(CNS*(x-mu)) + b ; write f32 + bf16 ----------------
__global__ __launch_bounds__(256) void k_centernorm(const float* __restrict__ x,
                                                    const float* __restrict__ g,
                                                    const float* __restrict__ bb,
                                                    float* __restrict__ of,
                                                    u16* __restrict__ ob) {
  const int row = blockIdx.x;
  const int t = threadIdx.x;
  const float* xr = x + (size_t)row * D_;
  f32x4 v0 = *(const f32x4*)(xr + t * 8);
  f32x4 v1 = *(const f32x4*)(xr + t * 8 + 4);
  float s = v0[0] + v0[1] + v0[2] + v0[3] + v1[0] + v1[1] + v1[2] + v1[3];
#pragma unroll
  for (int off = 1; off < 64; off <<= 1) s += __shfl_xor(s, off);
  __shared__ float red[4];
  if ((t & 63) == 0) red[t >> 6] = s;
  __syncthreads();
  const float mu = (red[0] + red[1] + red[2] + red[3]) * (1.0f / D_);
  const float CNS = (float)D_ / (float)(D_ - 1);
  f32x4 g0 = *(const f32x4*)(g + t * 8);
  f32x4 g1 = *(const f32x4*)(g + t * 8 + 4);
  f32x4 b0 = *(const f32x4*)(bb + t * 8);
  f32x4 b1 = *(const f32x4*)(bb + t * 8 + 4);
  f32x4 y0, y1;
  short8 yb;
#pragma unroll
  for (int i = 0; i < 4; i++) {
    y0[i] = g0[i] * (CNS * (v0[i] - mu)) + b0[i];
    y1[i] = g1[i] * (CNS * (v1[i] - mu)) + b1[i];
  }
#pragma unroll
  for (int i = 0; i < 4; i++) { yb[i] = (short)f2bf(y0[i]); yb[4 + i] = (short)f2bf(y1[i]); }
  float* orow = of + (size_t)row * D_;
  *(f32x4*)(orow + t * 8) = y0;
  *(f32x4*)(orow + t * 8 + 4) = y1;
  *(short8*)(ob + (size_t)row * D_ + t * 8) = yb;
}

// ---------------- l2norm q,k + head reorder; v convert ----------------
// [B,S,D] f32 -> [B,H,S,DH] bf16; one wave per (b,s,h)
__global__ __launch_bounds__(256) void k_l2norm(const float* __restrict__ q,
                                                const float* __restrict__ k,
                                                const float* __restrict__ v,
                                                u16* __restrict__ qn,
                                                u16* __restrict__ kn,
                                                u16* __restrict__ vn) {
  const int gw = blockIdx.x * 4 + (threadIdx.x >> 6);
  const int l = threadIdx.x & 63;
  const int h = gw & (H_ - 1);
  const int s = (gw >> 4) & (S_ - 1);
  const int b = gw >> 14;
  const size_t src = ((size_t)(b * S_ + s)) * D_ + h * DH_ + l * 2;
  const size_t dst = (((size_t)(b * H_ + h)) * S_ + s) * DH_ + l * 2;
  {
    f32x2 xv = *(const f32x2*)(q + src);
    float ss = xv[0] * xv[0] + xv[1] * xv[1];
#pragma unroll
    for (int off = 1; off < 64; off <<= 1) ss += __shfl_xor(ss, off);
    float sc = 1.f / (sqrtf(ss) + 1e-6f);
    u16x2 o; o[0] = f2bf(xv[0] * sc); o[1] = f2bf(xv[1] * sc);
    *(u16x2*)(qn + dst) = o;
  }
  {
    f32x2 xv = *(const f32x2*)(k + src);
    float ss = xv[0] * xv[0] + xv[1] * xv[1];
#pragma unroll
    for (int off = 1; off < 64; off <<= 1) ss += __shfl_xor(ss, off);
    float sc = 1.f / (sqrtf(ss) + 1e-6f);
    u16x2 o; o[0] = f2bf(xv[0] * sc); o[1] = f2bf(xv[1] * sc);
    *(u16x2*)(kn + dst) = o;
  }
  {
    f32x2 xv = *(const f32x2*)(v + src);
    u16x2 o; o[0] = f2bf(xv[0]); o[1] = f2bf(xv[1]);
    *(u16x2*)(vn + dst) = o;
  }
}

// ---------------- GEMM core: C[M,N] = A[M,K] * Bt[N,K]^T (+epilogue) ----------------
// EPI 0: outf = acc + bias
// EPI 1: outf = res + clip(alpha)*(acc + bias)
// EPI 2: outb = bf16(gelu(acc + bias))
template <int EPI>
__device__ __forceinline__ void gemm_core(const u16* __restrict__ A,
                                          const u16* __restrict__ Bt,
                                          const float* __restrict__ bias,
                                          const float* __restrict__ res,
                                          const float* __restrict__ alpha,
                                          float* __restrict__ outf,
                                          u16* __restrict__ outb, int N, int K) {
  __shared__ u16 As[128 * 32];
  __shared__ u16 Bs[128 * 32];
  const int t = threadIdx.x;
  const int l = t & 63;
  const int w = t >> 6;
  const int wr = w >> 1, wc = w & 1;
  const int l15 = l & 15, lhi = l >> 4;
  const int m0 = blockIdx.y * 128, n0 = blockIdx.x * 128;
  f32x4 acc[4][4] = {};
  const int srow = t >> 2;
  const int scol = (t & 3) * 8;
  const u16* Ag = A + (size_t)(m0 + srow) * K + scol;
  const u16* Ag2 = Ag + (size_t)64 * K;
  const u16* Bg = Bt + (size_t)(n0 + srow) * K + scol;
  const u16* Bg2 = Bg + (size_t)64 * K;
  char* lA = (char*)As + t * 16;
  char* lB = (char*)Bs + t * 16;
  for (int k0 = 0; k0 < K; k0 += 32) {
    gload16(Ag + k0, lA);
    gload16(Ag2 + k0, lA + 4096);
    gload16(Bg + k0, lB);
    gload16(Bg2 + k0, lB + 4096);
    __syncthreads();
    short8 af[4], bfr[4];
#pragma unroll
    for (int i = 0; i < 4; i++)
      af[i] = *(const short8*)(As + (wr * 64 + i * 16 + l15) * 32 + lhi * 8);
#pragma unroll
    for (int i = 0; i < 4; i++)
      bfr[i] = *(const short8*)(Bs + (wc * 64 + i * 16 + l15) * 32 + lhi * 8);
#pragma unroll
    for (int mi = 0; mi < 4; mi++)
#pragma unroll
      for (int ni = 0; ni < 4; ni++)
        acc[mi][ni] = __builtin_amdgcn_mfma_f32_16x16x32_bf16(af[mi], bfr[ni], acc[mi][ni], 0, 0, 0);
    __syncthreads();
  }
#pragma unroll
  for (int ni = 0; ni < 4; ni++) {
    const int col = n0 + wc * 64 + ni * 16 + l15;
    const float bcol = bias[col];
    float alc = 0.f;
    if (EPI == 1) alc = clipa(alpha[col]);
#pragma unroll
    for (int mi = 0; mi < 4; mi++) {
#pragma unroll
      for (int j = 0; j < 4; j++) {
        const int row = m0 + wr * 64 + mi * 16 + lhi * 4 + j;
        const float v = acc[mi][ni][j] + bcol;
        const size_t idx = (size_t)row * N + col;
        if (EPI == 0) outf[idx] = v;
        else if (EPI == 1) outf[idx] = res[idx] + alc * v;
        else outb[idx] = f2bf(gelu_f(v));
      }
    }
  }
}

__global__ __launch_bounds__(256) void k_gemm_qkv(const u16* A, const u16* W0, const u16* W1,
                                                  const u16* W2, const float* b0, const float* b1,
                                                  const float* b2, float* o0, float* o1, float* o2,
                                                  int N, int K) {
  const int z = blockIdx.z;
  const u16* Bt = z == 0 ? W0 : (z == 1 ? W1 : W2);
  const float* bias = z == 0 ? b0 : (z == 1 ? b1 : b2);
  float* out = z == 0 ? o0 : (z == 1 ? o1 : o2);
  gemm_core<0>(A, Bt, bias, nullptr, nullptr, out, nullptr, N, K);
}

__global__ __launch_bounds__(256) void k_gemm_res(const u16* A, const u16* Bt, const float* bias,
                                                  const float* res, const float* alpha,
                                                  float* outf, int N, int K) {
  gemm_core<1>(A, Bt, bias, res, alpha, outf, nullptr, N, K);
}

__global__ __launch_bounds__(256) void k_gemm_gelu(const u16* A, const u16* Bt, const float* bias,
                                                   u16* outb, int N, int K) {
  gemm_core<2>(A, Bt, bias, nullptr, nullptr, nullptr, outb, N, K);
}

// ---------------- attention: cosine attn, causal, online softmax ----------------
// grid (S/64, B*H), 256 thr. qn/kn/vn: [B,H,S,DH] bf16. o: [B,S,D] bf16.
__global__ __launch_bounds__(256) void k_attn(const u16* __restrict__ qn,
                                              const u16* __restrict__ kn,
                                              const u16* __restrict__ vn,
                                              const float* __restrict__ tau,
                                              const float* __restrict__ nu,
                                              u16* __restrict__ o) {
  __shared__ u16 Ks[64 * 128];   // row-major [kv][dh], XOR-swizzled
  __shared__ u16 Vt[128 * 64];   // transposed [dh][kv], XOR-swizzled
  __shared__ u16 Pl[4][16][72];  // per-wave P, +8 pad
  const int t = threadIdx.x;
  const int l = t & 63, w = t >> 6;
  const int l15 = l & 15, lhi = l >> 4;
  const int qt = blockIdx.x;
  const int bh = blockIdx.y;
  const int h = bh & (H_ - 1);
  const int b = bh >> 4;
  const size_t hoff = (size_t)bh * S_ * DH_;
  const u16* Qh = qn + hoff;
  const u16* Kh = kn + hoff;
  const u16* Vh = vn + hoff;
  const int q0 = qt * 64;
  const int r0 = q0 + w * 16;
  short8 qf[4];
#pragma unroll
  for (int kk = 0; kk < 4; kk++)
    qf[kk] = *(const short8*)(Qh + (size_t)(r0 + l15) * DH_ + kk * 32 + lhi * 8);
  const float taum = tau[h];
  float mrow[4], lrow[4];
  f32x4 oacc[8] = {};
#pragma unroll
  for (int j = 0; j < 4; j++) { mrow[j] = -1e30f; lrow[j] = 0.f; }

  for (int kv0 = 0; kv0 < q0 + 64; kv0 += 64) {
    // stage K (linear LDS dest, pre-swizzled global source; XOR is an involution)
#pragma unroll
    for (int i = 0; i < 4; i++) {
      const int p = i * 4096 + t * 16;
      const int row = p >> 8;
      const int colb = p & 255;
      const int scolb = colb ^ ((row & 7) << 4);
      gload16((const char*)(Kh + (size_t)(kv0 + row) * DH_) + scolb, (char*)Ks + p);
    }
    // stage V transposed via registers
#pragma unroll
    for (int i = 0; i < 4; i++) {
      const int c0 = w * 8 + i * 32;
      const int r = l;
      short8 vv = *(const short8*)(Vh + (size_t)(kv0 + r) * DH_ + c0);
#pragma unroll
      for (int j = 0; j < 8; j++) {
        const int ba = ((c0 + j) * 128 + r * 2) ^ (((c0 + j) & 7) << 4);
        *(u16*)((char*)Vt + ba) = (u16)vv[j];
      }
    }
    __syncthreads();
    // QK^T
    f32x4 st[4] = {};
#pragma unroll
    for (int ks = 0; ks < 4; ks++) {
#pragma unroll
      for (int ct = 0; ct < 4; ct++) {
        const int n = ct * 16 + l15;
        const int ka = (ks * 32 + lhi * 8) * 2;
        short8 kf = *(const short8*)((const char*)Ks + n * 256 + (ka ^ ((n & 7) << 4)));
        st[ct] = __builtin_amdgcn_mfma_f32_16x16x32_bf16(qf[ks], kf, st[ct], 0, 0, 0);
      }
    }
    // mask + tau
    float pm[4] = {-1e30f, -1e30f, -1e30f, -1e30f};
#pragma unroll
    for (int ct = 0; ct < 4; ct++) {
      const int col = kv0 + ct * 16 + l15;
#pragma unroll
      for (int j = 0; j < 4; j++) {
        const int row = r0 + lhi * 4 + j;
        float s = st[ct][j] * taum;
        s = (col <= row) ? s : -1e30f;
        st[ct][j] = s;
        pm[j] = fmaxf(pm[j], s);
      }
    }
#pragma unroll
    for (int j = 0; j < 4; j++) {
#pragma unroll
      for (int off = 1; off < 16; off <<= 1) pm[j] = fmaxf(pm[j], __shfl_xor(pm[j], off));
    }
    float scl[4], psum[4];
#pragma unroll
    for (int j = 0; j < 4; j++) {
      const float nm = fmaxf(mrow[j], pm[j]);
      scl[j] = __expf(mrow[j] - nm);
      mrow[j] = nm;
      psum[j] = 0.f;
    }
#pragma unroll
    for (int ct = 0; ct < 4; ct++) {
#pragma unroll
      for (int j = 0; j < 4; j++) {
        const float p = __expf(st[ct][j] - mrow[j]);
        psum[j] += p;
        Pl[w][lhi * 4 + j][ct * 16 + l15] = f2bf(p);
      }
    }
#pragma unroll
    for (int j = 0; j < 4; j++) {
#pragma unroll
      for (int off = 1; off < 16; off <<= 1) psum[j] += __shfl_xor(psum[j], off);
      lrow[j] = lrow[j] * scl[j] + psum[j];
    }
#pragma unroll
    for (int nt = 0; nt < 8; nt++) {
#pragma unroll
      for (int j = 0; j < 4; j++) oacc[nt][j] *= scl[j];
    }
    // PV
#pragma unroll
    for (int ks2 = 0; ks2 < 2; ks2++) {
      short8 pa = *(const short8*)((const char*)&Pl[w][0][0] + l15 * 144 + ks2 * 64 + lhi * 16);
#pragma unroll
      for (int nt = 0; nt < 8; nt++) {
        const int n = nt * 16 + l15;
        const int ba = (n * 128 + (ks2 * 32 + lhi * 8) * 2) ^ ((n & 7) << 4);
        short8 vf = *(const short8*)((const char*)Vt + ba);
        oacc[nt] = __builtin_amdgcn_mfma_f32_16x16x32_bf16(pa, vf, oacc[nt], 0, 0, 0);
      }
    }
    __syncthreads();
  }
  const float num = nu[h];
  float rs[4];
#pragma unroll
  for (int j = 0; j < 4; j++) rs[j] = num / lrow[j];
#pragma unroll
  for (int nt = 0; nt < 8; nt++) {
    const int col = h * DH_ + nt * 16 + l15;
#pragma unroll
    for (int j = 0; j < 4; j++) {
      const int row = r0 + lhi * 4 + j;
      o[((size_t)b * S_ + row) * D_ + col] = f2bf(oacc[nt][j] * rs[j]);
    }
  }
}

// ---------------- launch ----------------
extern "C" void kernel_launch(void* const* d_in, const int* in_sizes, int n_in,
                              void* d_out, int out_size, void* d_ws, size_t ws_size,
                              hipStream_t stream) {
  const float* x    = (const float*)d_in[0];
  const float* ln1g = (const float*)d_in[1];
  const float* ln1b = (const float*)d_in[2];
  const float* wq   = (const float*)d_in[3];
  const float* bq   = (const float*)d_in[4];
  const float* wk   = (const float*)d_in[5];
  const float* bk   = (const float*)d_in[6];
  const float* wv   = (const float*)d_in[7];
  const float* bv   = (const float*)d_in[8];
  const float* wo   = (const float*)d_in[9];
  const float* bo   = (const float*)d_in[10];
  const float* tau  = (const float*)d_in[11];
  const float* nu   = (const float*)d_in[12];
  const float* al1  = (const float*)d_in[13];
  const float* ln2g = (const float*)d_in[14];
  const float* ln2b = (const float*)d_in[15];
  const float* w1   = (const float*)d_in[16];
  const float* b1   = (const float*)d_in[17];
  const float* w2   = (const float*)d_in[18];
  const float* b2   = (const float*)d_in[19];
  const float* al2  = (const float*)d_in[20];

  char* ws = (char*)d_ws;
  u16* WQ = (u16*)(ws + 0);
  u16* WK = (u16*)(ws + 8388608);
  u16* WV = (u16*)(ws + 16777216);
  u16* WO = (u16*)(ws + 25165824);
  u16* W1B = (u16*)(ws + 33554432);
  u16* W2B = (u16*)(ws + 67108864);
  float* AF = (float*)(ws + 100663296);   // centernorm1 f32
  u16*   AB = (u16*)(ws + 117440512);     // centernorm1 bf16
  float* QF = (float*)(ws + 125829120);
  float* KF = (float*)(ws + 142606336);
  float* VF = (float*)(ws + 159383552);
  u16* QN = (u16*)(ws + 176160768);
  u16* KN = (u16*)(ws + 184549376);
  u16* VN = (u16*)(ws + 192937984);
  // reuse after l2norm / attention:
  u16*   OB = (u16*)(ws + 125829120);     // attn out bf16 (over QF)
  u16*   MB = (u16*)(ws + 134217728);     // centernorm2 bf16 (over QF hi half)
  float* X1 = (float*)(ws + 142606336);   // residual1 f32 (over KF)
  float* MF = (float*)(ws + 159383552);   // centernorm2 f32 (over VF)
  u16*   HB = (u16*)(ws + 176160768);     // ffn hidden bf16 (over QN..)

  // weights -> bf16
  k_cvt<<<2048, 256, 0, stream>>>(wq, WQ, 524288);
  k_cvt<<<2048, 256, 0, stream>>>(wk, WK, 524288);
  k_cvt<<<2048, 256, 0, stream>>>(wv, WV, 524288);
  k_cvt<<<2048, 256, 0, stream>>>(wo, WO, 524288);
  k_cvt<<<8192, 256, 0, stream>>>(w1, W1B, 2097152);
  k_cvt<<<8192, 256, 0, stream>>>(w2, W2B, 2097152);

  // centernorm 1
  k_centernorm<<<M_, 256, 0, stream>>>(x, ln1g, ln1b, AF, AB);

  // qkv projections
  k_gemm_qkv<<<dim3(16, 16, 3), 256, 0, stream>>>(AB, WQ, WK, WV, bq, bk, bv,
                                                  QF, KF, VF, D_, D_);

  // l2norm + head reorder
  k_l2norm<<<8192, 256, 0, stream>>>(QF, KF, VF, QN, KN, VN);

  // attention
  k_attn<<<dim3(S_ / 64, B_ * H_), 256, 0, stream>>>(QN, KN, VN, tau, nu, OB);

  // output projection + residual (x1 = a + a1*attn)
  k_gemm_res<<<dim3(16, 16), 256, 0, stream>>>(OB, WO, bo, AF, al1, X1, D_, D_);

  // centernorm 2
  k_centernorm<<<M_, 256, 0, stream>>>(X1, ln2g, ln2b, MF, MB);

  // ffn1 (gelu -> bf16)
  k_gemm_gelu<<<dim3(64, 16), 256, 0, stream>>>(MB, W1B, b1, HB, F_, D_);

  // ffn2 + residual (out = m + a2*ffn)
  k_gemm_res<<<dim3(16, 16), 256, 0, stream>>>(HB, W2B, b2, MF, al2, (float*)d_out, D_, F_);
}

// Round 2
// 502.760 us; speedup vs baseline: 1.1100x; 1.1100x over previous
//
#include <hip/hip_runtime.h>
#include <hip/hip_bf16.h>
#include <stdint.h>

#define B_ 2
#define S_ 1024
#define D_ 2048
#define H_ 16
#define F_ 8192
#define DH_ 128
#define M_ 2048  // B*S

typedef unsigned short u16;
typedef __attribute__((ext_vector_type(8))) short short8;
typedef __attribute__((ext_vector_type(4))) float f32x4;
typedef __attribute__((ext_vector_type(2))) float f32x2;
typedef __attribute__((ext_vector_type(2))) unsigned short u16x2;

__device__ __forceinline__ u16 f2bf(float f) {
  union { float f; uint32_t u; } c; c.f = f;
  uint32_t r = c.u + 0x7FFFu + ((c.u >> 16) & 1u);
  return (u16)(r >> 16);
}

__device__ __forceinline__ void gload16(const void* g, void* l) {
  __builtin_amdgcn_global_load_lds((const __attribute__((address_space(1))) void*)g,
                                   (__attribute__((address_space(3))) void*)l, 16, 0, 0);
}

__device__ __forceinline__ float clipa(float a) {
  return fminf(0.2f, fmaxf(-0.2f, a));
}

__device__ __forceinline__ float gelu_f(float x) {
  float z = 0.7978845608028654f * (x + 0.044715f * x * x * x);
  z = fminf(10.f, fmaxf(-10.f, z));
  float e = __expf(2.f * z);
  return 0.5f * x * (1.f + (e - 1.f) / (e + 1.f));
}

// ---------------- f32 -> bf16 vector convert ----------------
__global__ __launch_bounds__(256) void k_cvt(const float* __restrict__ s,
                                             u16* __restrict__ d, int n8) {
  int i = blockIdx.x * 256 + threadIdx.x;
  if (i >= n8) return;
  f32x4 a = *(const f32x4*)(s + (size_t)i * 8);
  f32x4 b = *(const f32x4*)(s + (size_t)i * 8 + 4);
  short8 o;
  o[0] = (short)f2bf(a[0]); o[1] = (short)f2bf(a[1]);
  o[2] = (short)f2bf(a[2]); o[3] = (short)f2bf(a[3]);
  o[4] = (short)f2bf(b[0]); o[5] = (short)f2bf(b[1]);
  o[6] = (short)f2bf(b[2]); o[7] = (short)f2bf(b[3]);
  *(short8*)(d + (size_t)i * 8) = o;
}

// ---------------- CenterNorm ----------------
__global__ __launch_bounds__(256) void k_centernorm(const float* __restrict__ x,
                                                    const float* __restrict__ g,
                                                    const float* __restrict__ bb,
                                                    float* __restrict__ of,
                                                    u16* __restrict__ ob) {
  const int row = blockIdx.x;
  const int t = threadIdx.x;
  const float* xr = x + (size_t)row * D_;
  f32x4 v0 = *(const f32x4*)(xr + t * 8);
  f32x4 v1 = *(const f32x4*)(xr + t * 8 + 4);
  float s = v0[0] + v0[1] + v0[2] + v0[3] + v1[0] + v1[1] + v1[2] + v1[3];
#pragma unroll
  for (int off = 1; off < 64; off <<= 1) s += __shfl_xor(s, off);
  __shared__ float red[4];
  if ((t & 63) == 0) red[t >> 6] = s;
  __syncthreads();
  const float mu = (red[0] + red[1] + red[2] + red[3]) * (1.0f / D_);
  const float CNS = (float)D_ / (float)(D_ - 1);
  f32x4 g0 = *(const f32x4*)(g + t * 8);
  f32x4 g1 = *(const f32x4*)(g + t * 8 + 4);
  f32x4 b0 = *(const f32x4*)(bb + t * 8);
  f32x4 b1 = *(const f32x4*)(bb + t * 8 + 4);
  f32x4 y0, y1;
  short8 yb;
#pragma unroll
  for (int i = 0; i < 4; i++) {
    y0[i] = g0[i] * (CNS * (v0[i] - mu)) + b0[i];
    y1[i] = g1[i] * (CNS * (v1[i] - mu)) + b1[i];
  }
#pragma unroll
  for (int i = 0; i < 4; i++) { yb[i] = (short)f2bf(y0[i]); yb[4 + i] = (short)f2bf(y1[i]); }
  float* orow = of + (size_t)row * D_;
  *(f32x4*)(orow + t * 8) = y0;
  *(f32x4*)(orow + t * 8 + 4) = y1;
  *(short8*)(ob + (size_t)row * D_ + t * 8) = yb;
}

// ---------------- l2norm q,k + head reorder; v convert ----------------
__global__ __launch_bounds__(256) void k_l2norm(const float* __restrict__ q,
                                                const float* __restrict__ k,
                                                const float* __restrict__ v,
                                                u16* __restrict__ qn,
                                                u16* __restrict__ kn,
                                                u16* __restrict__ vn) {
  const int gw = blockIdx.x * 4 + (threadIdx.x >> 6);
  const int l = threadIdx.x & 63;
  const int h = gw & (H_ - 1);
  const int s = (gw >> 4) & (S_ - 1);
  const int b = gw >> 14;
  const size_t src = ((size_t)(b * S_ + s)) * D_ + h * DH_ + l * 2;
  const size_t dst = (((size_t)(b * H_ + h)) * S_ + s) * DH_ + l * 2;
  {
    f32x2 xv = *(const f32x2*)(q + src);
    float ss = xv[0] * xv[0] + xv[1] * xv[1];
#pragma unroll
    for (int off = 1; off < 64; off <<= 1) ss += __shfl_xor(ss, off);
    float sc = 1.f / (sqrtf(ss) + 1e-6f);
    u16x2 o; o[0] = f2bf(xv[0] * sc); o[1] = f2bf(xv[1] * sc);
    *(u16x2*)(qn + dst) = o;
  }
  {
    f32x2 xv = *(const f32x2*)(k + src);
    float ss = xv[0] * xv[0] + xv[1] * xv[1];
#pragma unroll
    for (int off = 1; off < 64; off <<= 1) ss += __shfl_xor(ss, off);
    float sc = 1.f / (sqrtf(ss) + 1e-6f);
    u16x2 o; o[0] = f2bf(xv[0] * sc); o[1] = f2bf(xv[1] * sc);
    *(u16x2*)(kn + dst) = o;
  }
  {
    f32x2 xv = *(const f32x2*)(v + src);
    u16x2 o; o[0] = f2bf(xv[0]); o[1] = f2bf(xv[1]);
    *(u16x2*)(vn + dst) = o;
  }
}

// ---------------- GEMM core: C[M,N] = A[M,K(sub)] * Bt[N,K]^T (+epilogue) ----------------
// 2-phase double-buffered pipeline (T3-min): stage next tile before compute of current.
// EPI 0: outf = acc + bias
// EPI 1: outf = res + clip(alpha)*(acc + bias)
// EPI 2: outb = bf16(gelu(acc + bias))
// EPI 3: outf = acc (raw partial, split-K)
template <int EPI>
__device__ __forceinline__ void gemm_core(const u16* __restrict__ A,
                                          const u16* __restrict__ Bt,
                                          const float* __restrict__ bias,
                                          const float* __restrict__ res,
                                          const float* __restrict__ alpha,
                                          float* __restrict__ outf,
                                          u16* __restrict__ outb, int N, int K,
                                          int kbase, int kiters) {
  __shared__ u16 As[2][128 * 32];
  __shared__ u16 Bs[2][128 * 32];
  const int t = threadIdx.x;
  const int l = t & 63;
  const int w = t >> 6;
  const int wr = w >> 1, wc = w & 1;
  const int l15 = l & 15, lhi = l >> 4;
  const int m0 = blockIdx.y * 128, n0 = blockIdx.x * 128;
  f32x4 acc[4][4] = {};
  const int srow = t >> 2;
  const int scol = (t & 3) * 8;
  const u16* Ag = A + (size_t)(m0 + srow) * K + kbase + scol;
  const u16* Ag2 = Ag + (size_t)64 * K;
  const u16* Bg = Bt + (size_t)(n0 + srow) * K + kbase + scol;
  const u16* Bg2 = Bg + (size_t)64 * K;
  const int loff = t * 16;

  // prologue: stage tile 0 into buf 0
  gload16(Ag, (char*)As[0] + loff);
  gload16(Ag2, (char*)As[0] + 4096 + loff);
  gload16(Bg, (char*)Bs[0] + loff);
  gload16(Bg2, (char*)Bs[0] + 4096 + loff);
  __syncthreads();

  int cur = 0;
  for (int it = 0; it < kiters; ++it) {
    // stage next tile into the other buffer BEFORE computing current
    if (it + 1 < kiters) {
      const int k0 = (it + 1) * 32;
      char* dA = (char*)As[cur ^ 1] + loff;
      char* dB = (char*)Bs[cur ^ 1] + loff;
      gload16(Ag + k0, dA);
      gload16(Ag2 + k0, dA + 4096);
      gload16(Bg + k0, dB);
      gload16(Bg2 + k0, dB + 4096);
    }
    short8 af[4], bfr[4];
#pragma unroll
    for (int i = 0; i < 4; i++)
      af[i] = *(const short8*)(As[cur] + (wr * 64 + i * 16 + l15) * 32 + lhi * 8);
#pragma unroll
    for (int i = 0; i < 4; i++)
      bfr[i] = *(const short8*)(Bs[cur] + (wc * 64 + i * 16 + l15) * 32 + lhi * 8);
#pragma unroll
    for (int mi = 0; mi < 4; mi++)
#pragma unroll
      for (int ni = 0; ni < 4; ni++)
        acc[mi][ni] = __builtin_amdgcn_mfma_f32_16x16x32_bf16(af[mi], bfr[ni], acc[mi][ni], 0, 0, 0);
    __syncthreads();  // drains vmcnt(0) -> next buffer ready; reads of cur done
    cur ^= 1;
  }
#pragma unroll
  for (int ni = 0; ni < 4; ni++) {
    const int col = n0 + wc * 64 + ni * 16 + l15;
    const float bcol = (EPI == 3) ? 0.f : bias[col];
    float alc = 0.f;
    if (EPI == 1) alc = clipa(alpha[col]);
#pragma unroll
    for (int mi = 0; mi < 4; mi++) {
#pragma unroll
      for (int j = 0; j < 4; j++) {
        const int row = m0 + wr * 64 + mi * 16 + lhi * 4 + j;
        const float v = acc[mi][ni][j] + bcol;
        const size_t idx = (size_t)row * N + col;
        if (EPI == 0) outf[idx] = v;
        else if (EPI == 1) outf[idx] = res[idx] + alc * v;
        else if (EPI == 2) outb[idx] = f2bf(gelu_f(v));
        else outf[idx] = v;
      }
    }
  }
}

__global__ __launch_bounds__(256) void k_qkv(const u16* A, const u16* W0, const u16* W1,
                                             const u16* W2, const float* b0, const float* b1,
                                             const float* b2, float* o0, float* o1, float* o2) {
  const int z = blockIdx.z;
  const u16* Bt = z == 0 ? W0 : (z == 1 ? W1 : W2);
  const float* bias = z == 0 ? b0 : (z == 1 ? b1 : b2);
  float* out = z == 0 ? o0 : (z == 1 ? o1 : o2);
  gemm_core<0>(A, Bt, bias, nullptr, nullptr, out, nullptr, D_, D_, 0, D_ / 32);
}

__global__ __launch_bounds__(256) void k_oproj(const u16* A, const u16* Bt, const float* bias,
                                               const float* res, const float* alpha,
                                               float* outf) {
  gemm_core<1>(A, Bt, bias, res, alpha, outf, nullptr, D_, D_, 0, D_ / 32);
}

__global__ __launch_bounds__(256) void k_ffn1(const u16* A, const u16* Bt, const float* bias,
                                              u16* outb) {
  gemm_core<2>(A, Bt, bias, nullptr, nullptr, nullptr, outb, F_, D_, 0, D_ / 32);
}

__global__ __launch_bounds__(256) void k_ffn2(const u16* A, const u16* Bt, float* P) {
  const int z = blockIdx.z;
  float* out = P + (size_t)z * M_ * D_;
  gemm_core<3>(A, Bt, nullptr, nullptr, nullptr, out, nullptr, D_, F_, z * 2048, 64);
}

// out = res + clip(alpha)*(sum_z P[z] + bias)
__global__ __launch_bounds__(256) void k_ffn2_combine(const float* __restrict__ P,
                                                      const float* __restrict__ bias,
                                                      const float* __restrict__ res,
                                                      const float* __restrict__ alpha,
                                                      float* __restrict__ out) {
  const int i = blockIdx.x * 256 + threadIdx.x;
  const size_t base = (size_t)i * 8;
  const int col = (int)(base & (D_ - 1));
  const size_t PS = (size_t)M_ * D_;
  f32x4 s0 = {}, s1 = {};
#pragma unroll
  for (int p = 0; p < 4; p++) {
    s0 += *(const f32x4*)(P + p * PS + base);
    s1 += *(const f32x4*)(P + p * PS + base + 4);
  }
  f32x4 b0 = *(const f32x4*)(bias + col);
  f32x4 b1 = *(const f32x4*)(bias + col + 4);
  f32x4 a0 = *(const f32x4*)(alpha + col);
  f32x4 a1 = *(const f32x4*)(alpha + col + 4);
  f32x4 r0 = *(const f32x4*)(res + base);
  f32x4 r1 = *(const f32x4*)(res + base + 4);
  f32x4 o0, o1;
#pragma unroll
  for (int j = 0; j < 4; j++) {
    o0[j] = r0[j] + clipa(a0[j]) * (s0[j] + b0[j]);
    o1[j] = r1[j] + clipa(a1[j]) * (s1[j] + b1[j]);
  }
  *(f32x4*)(out + base) = o0;
  *(f32x4*)(out + base + 4) = o1;
}

// ---------------- attention: cosine attn, causal, online softmax ----------------
__global__ __launch_bounds__(256) void k_attn(const u16* __restrict__ qn,
                                              const u16* __restrict__ kn,
                                              const u16* __restrict__ vn,
                                              const float* __restrict__ tau,
                                              const float* __restrict__ nu,
                                              u16* __restrict__ o) {
  __shared__ u16 Ks[64 * 128];   // row-major [kv][dh], XOR-swizzled
  __shared__ u16 Vt[128 * 64];   // transposed [dh][kv], XOR-swizzled
  __shared__ u16 Pl[4][16][72];  // per-wave P, +8 pad
  const int t = threadIdx.x;
  const int l = t & 63, w = t >> 6;
  const int l15 = l & 15, lhi = l >> 4;
  const int qt = blockIdx.x;
  const int bh = blockIdx.y;
  const int h = bh & (H_ - 1);
  const int b = bh >> 4;
  const size_t hoff = (size_t)bh * S_ * DH_;
  const u16* Qh = qn + hoff;
  const u16* Kh = kn + hoff;
  const u16* Vh = vn + hoff;
  const int q0 = qt * 64;
  const int r0 = q0 + w * 16;
  short8 qf[4];
#pragma unroll
  for (int kk = 0; kk < 4; kk++)
    qf[kk] = *(const short8*)(Qh + (size_t)(r0 + l15) * DH_ + kk * 32 + lhi * 8);
  const float taum = tau[h];
  float mrow[4], lrow[4];
  f32x4 oacc[8] = {};
#pragma unroll
  for (int j = 0; j < 4; j++) { mrow[j] = -1e30f; lrow[j] = 0.f; }

  for (int kv0 = 0; kv0 < q0 + 64; kv0 += 64) {
#pragma unroll
    for (int i = 0; i < 4; i++) {
      const int p = i * 4096 + t * 16;
      const int row = p >> 8;
      const int colb = p & 255;
      const int scolb = colb ^ ((row & 7) << 4);
      gload16((const char*)(Kh + (size_t)(kv0 + row) * DH_) + scolb, (char*)Ks + p);
    }
#pragma unroll
    for (int i = 0; i < 4; i++) {
      const int c0 = w * 8 + i * 32;
      const int r = l;
      short8 vv = *(const short8*)(Vh + (size_t)(kv0 + r) * DH_ + c0);
#pragma unroll
      for (int j = 0; j < 8; j++) {
        const int ba = ((c0 + j) * 128 + r * 2) ^ (((c0 + j) & 7) << 4);
        *(u16*)((char*)Vt + ba) = (u16)vv[j];
      }
    }
    __syncthreads();
    f32x4 st[4] = {};
#pragma unroll
    for (int ks = 0; ks < 4; ks++) {
#pragma unroll
      for (int ct = 0; ct < 4; ct++) {
        const int n = ct * 16 + l15;
        const int ka = (ks * 32 + lhi * 8) * 2;
        short8 kf = *(const short8*)((const char*)Ks + n * 256 + (ka ^ ((n & 7) << 4)));
        st[ct] = __builtin_amdgcn_mfma_f32_16x16x32_bf16(qf[ks], kf, st[ct], 0, 0, 0);
      }
    }
    float pm[4] = {-1e30f, -1e30f, -1e30f, -1e30f};
#pragma unroll
    for (int ct = 0; ct < 4; ct++) {
      const int col = kv0 + ct * 16 + l15;
#pragma unroll
      for (int j = 0; j < 4; j++) {
        const int row = r0 + lhi * 4 + j;
        float s = st[ct][j] * taum;
        s = (col <= row) ? s : -1e30f;
        st[ct][j] = s;
        pm[j] = fmaxf(pm[j], s);
      }
    }
#pragma unroll
    for (int j = 0; j < 4; j++) {
#pragma unroll
      for (int off = 1; off < 16; off <<= 1) pm[j] = fmaxf(pm[j], __shfl_xor(pm[j], off));
    }
    float scl[4], psum[4];
#pragma unroll
    for (int j = 0; j < 4; j++) {
      const float nm = fmaxf(mrow[j], pm[j]);
      scl[j] = __expf(mrow[j] - nm);
      mrow[j] = nm;
      psum[j] = 0.f;
    }
#pragma unroll
    for (int ct = 0; ct < 4; ct++) {
#pragma unroll
      for (int j = 0; j < 4; j++) {
        const float p = __expf(st[ct][j] - mrow[j]);
        psum[j] += p;
        Pl[w][lhi * 4 + j][ct * 16 + l15] = f2bf(p);
      }
    }
#pragma unroll
    for (int j = 0; j < 4; j++) {
#pragma unroll
      for (int off = 1; off < 16; off <<= 1) psum[j] += __shfl_xor(psum[j], off);
      lrow[j] = lrow[j] * scl[j] + psum[j];
    }
#pragma unroll
    for (int nt = 0; nt < 8; nt++) {
#pragma unroll
      for (int j = 0; j < 4; j++) oacc[nt][j] *= scl[j];
    }
#pragma unroll
    for (int ks2 = 0; ks2 < 2; ks2++) {
      short8 pa = *(const short8*)((const char*)&Pl[w][0][0] + l15 * 144 + ks2 * 64 + lhi * 16);
#pragma unroll
      for (int nt = 0; nt < 8; nt++) {
        const int n = nt * 16 + l15;
        const int ba = (n * 128 + (ks2 * 32 + lhi * 8) * 2) ^ ((n & 7) << 4);
        short8 vf = *(const short8*)((const char*)Vt + ba);
        oacc[nt] = __builtin_amdgcn_mfma_f32_16x16x32_bf16(pa, vf, oacc[nt], 0, 0, 0);
      }
    }
    __syncthreads();
  }
  const float num = nu[h];
  float rs[4];
#pragma unroll
  for (int j = 0; j < 4; j++) rs[j] = num / lrow[j];
#pragma unroll
  for (int nt = 0; nt < 8; nt++) {
    const int col = h * DH_ + nt * 16 + l15;
#pragma unroll
    for (int j = 0; j < 4; j++) {
      const int row = r0 + lhi * 4 + j;
      o[((size_t)b * S_ + row) * D_ + col] = f2bf(oacc[nt][j] * rs[j]);
    }
  }
}

// ---------------- launch ----------------
extern "C" void kernel_launch(void* const* d_in, const int* in_sizes, int n_in,
                              void* d_out, int out_size, void* d_ws, size_t ws_size,
                              hipStream_t stream) {
  const float* x    = (const float*)d_in[0];
  const float* ln1g = (const float*)d_in[1];
  const float* ln1b = (const float*)d_in[2];
  const float* wq   = (const float*)d_in[3];
  const float* bq   = (const float*)d_in[4];
  const float* wk   = (const float*)d_in[5];
  const float* bk   = (const float*)d_in[6];
  const float* wv   = (const float*)d_in[7];
  const float* bv   = (const float*)d_in[8];
  const float* wo   = (const float*)d_in[9];
  const float* bo   = (const float*)d_in[10];
  const float* tau  = (const float*)d_in[11];
  const float* nu   = (const float*)d_in[12];
  const float* al1  = (const float*)d_in[13];
  const float* ln2g = (const float*)d_in[14];
  const float* ln2b = (const float*)d_in[15];
  const float* w1   = (const float*)d_in[16];
  const float* b1   = (const float*)d_in[17];
  const float* w2   = (const float*)d_in[18];
  const float* b2   = (const float*)d_in[19];
  const float* al2  = (const float*)d_in[20];

  char* ws = (char*)d_ws;
  u16* WQ = (u16*)(ws + 0);
  u16* WK = (u16*)(ws + 8388608);
  u16* WV = (u16*)(ws + 16777216);
  u16* WO = (u16*)(ws + 25165824);
  u16* W1B = (u16*)(ws + 33554432);
  u16* W2B = (u16*)(ws + 67108864);
  float* AF = (float*)(ws + 100663296);   // centernorm1 f32
  u16*   AB = (u16*)(ws + 117440512);     // centernorm1 bf16
  float* QF = (float*)(ws + 125829120);
  float* KF = (float*)(ws + 142606336);
  float* VF = (float*)(ws + 159383552);
  u16* QN = (u16*)(ws + 176160768);
  u16* KN = (u16*)(ws + 184549376);
  u16* VN = (u16*)(ws + 192937984);
  // reuse after l2norm / attention:
  u16*   OB = (u16*)(ws + 125829120);     // attn out bf16 (over QF)
  u16*   MB = (u16*)(ws + 134217728);     // centernorm2 bf16 (over QF hi half)
  float* X1 = (float*)(ws + 142606336);   // residual1 f32 (over KF)
  float* MF = (float*)(ws + 159383552);   // centernorm2 f32 (over VF)
  u16*   HB = (u16*)(ws + 176160768);     // ffn hidden bf16 (over QN..)
  float* P4 = (float*)(ws + 0);           // ffn2 split-K partials, 4x16MB (over dead WQ..W1B)

  // weights -> bf16
  k_cvt<<<2048, 256, 0, stream>>>(wq, WQ, 524288);
  k_cvt<<<2048, 256, 0, stream>>>(wk, WK, 524288);
  k_cvt<<<2048, 256, 0, stream>>>(wv, WV, 524288);
  k_cvt<<<2048, 256, 0, stream>>>(wo, WO, 524288);
  k_cvt<<<8192, 256, 0, stream>>>(w1, W1B, 2097152);
  k_cvt<<<8192, 256, 0, stream>>>(w2, W2B, 2097152);

  // centernorm 1
  k_centernorm<<<M_, 256, 0, stream>>>(x, ln1g, ln1b, AF, AB);

  // qkv projections
  k_qkv<<<dim3(16, 16, 3), 256, 0, stream>>>(AB, WQ, WK, WV, bq, bk, bv, QF, KF, VF);

  // l2norm + head reorder
  k_l2norm<<<8192, 256, 0, stream>>>(QF, KF, VF, QN, KN, VN);

  // attention
  k_attn<<<dim3(S_ / 64, B_ * H_), 256, 0, stream>>>(QN, KN, VN, tau, nu, OB);

  // output projection + residual (x1 = a + a1*attn)
  k_oproj<<<dim3(16, 16), 256, 0, stream>>>(OB, WO, bo, AF, al1, X1);

  // centernorm 2
  k_centernorm<<<M_, 256, 0, stream>>>(X1, ln2g, ln2b, MF, MB);

  // ffn1 (gelu -> bf16)
  k_ffn1<<<dim3(64, 16), 256, 0, stream>>>(MB, W1B, b1, HB);

  // ffn2 split-K=4 partials + combine (out = m + a2*(sum+bias))
  k_ffn2<<<dim3(16, 16, 4), 256, 0, stream>>>(HB, W2B, P4);
  k_ffn2_combine<<<2048, 256, 0, stream>>>(P4, b2, MF, al2, (float*)d_out);
}

// Round 3
// 422.987 us; speedup vs baseline: 1.3193x; 1.1886x over previous
//
#include <hip/hip_runtime.h>
#include <hip/hip_bf16.h>
#include <stdint.h>

#define B_ 2
#define S_ 1024
#define D_ 2048
#define H_ 16
#define F_ 8192
#define DH_ 128
#define M_ 2048  // B*S

typedef unsigned short u16;
typedef __attribute__((ext_vector_type(8))) short short8;
typedef __attribute__((ext_vector_type(4))) float f32x4;
typedef __attribute__((ext_vector_type(2))) float f32x2;
typedef __attribute__((ext_vector_type(2))) unsigned short u16x2;

__device__ __forceinline__ u16 f2bf(float f) {
  union { float f; uint32_t u; } c; c.f = f;
  uint32_t r = c.u + 0x7FFFu + ((c.u >> 16) & 1u);
  return (u16)(r >> 16);
}

__device__ __forceinline__ void gload16(const void* g, void* l) {
  __builtin_amdgcn_global_load_lds((const __attribute__((address_space(1))) void*)g,
                                   (__attribute__((address_space(3))) void*)l, 16, 0, 0);
}

__device__ __forceinline__ float clipa(float a) {
  return fminf(0.2f, fmaxf(-0.2f, a));
}

__device__ __forceinline__ float gelu_f(float x) {
  float z = 0.7978845608028654f * (x + 0.044715f * x * x * x);
  z = fminf(10.f, fmaxf(-10.f, z));
  float e = __expf(2.f * z);
  return 0.5f * x * (1.f + (e - 1.f) / (e + 1.f));
}

// ---------------- f32 -> bf16 vector convert ----------------
__global__ __launch_bounds__(256) void k_cvt(const float* __restrict__ s,
                                             u16* __restrict__ d, int n8) {
  int i = blockIdx.x * 256 + threadIdx.x;
  if (i >= n8) return;
  f32x4 a = *(const f32x4*)(s + (size_t)i * 8);
  f32x4 b = *(const f32x4*)(s + (size_t)i * 8 + 4);
  short8 o;
  o[0] = (short)f2bf(a[0]); o[1] = (short)f2bf(a[1]);
  o[2] = (short)f2bf(a[2]); o[3] = (short)f2bf(a[3]);
  o[4] = (short)f2bf(b[0]); o[5] = (short)f2bf(b[1]);
  o[6] = (short)f2bf(b[2]); o[7] = (short)f2bf(b[3]);
  *(short8*)(d + (size_t)i * 8) = o;
}

// ---------------- CenterNorm ----------------
__global__ __launch_bounds__(256) void k_centernorm(const float* __restrict__ x,
                                                    const float* __restrict__ g,
                                                    const float* __restrict__ bb,
                                                    float* __restrict__ of,
                                                    u16* __restrict__ ob) {
  const int row = blockIdx.x;
  const int t = threadIdx.x;
  const float* xr = x + (size_t)row * D_;
  f32x4 v0 = *(const f32x4*)(xr + t * 8);
  f32x4 v1 = *(const f32x4*)(xr + t * 8 + 4);
  float s = v0[0] + v0[1] + v0[2] + v0[3] + v1[0] + v1[1] + v1[2] + v1[3];
#pragma unroll
  for (int off = 1; off < 64; off <<= 1) s += __shfl_xor(s, off);
  __shared__ float red[4];
  if ((t & 63) == 0) red[t >> 6] = s;
  __syncthreads();
  const float mu = (red[0] + red[1] + red[2] + red[3]) * (1.0f / D_);
  const float CNS = (float)D_ / (float)(D_ - 1);
  f32x4 g0 = *(const f32x4*)(g + t * 8);
  f32x4 g1 = *(const f32x4*)(g + t * 8 + 4);
  f32x4 b0 = *(const f32x4*)(bb + t * 8);
  f32x4 b1 = *(const f32x4*)(bb + t * 8 + 4);
  f32x4 y0, y1;
  short8 yb;
#pragma unroll
  for (int i = 0; i < 4; i++) {
    y0[i] = g0[i] * (CNS * (v0[i] - mu)) + b0[i];
    y1[i] = g1[i] * (CNS * (v1[i] - mu)) + b1[i];
  }
#pragma unroll
  for (int i = 0; i < 4; i++) { yb[i] = (short)f2bf(y0[i]); yb[4 + i] = (short)f2bf(y1[i]); }
  float* orow = of + (size_t)row * D_;
  *(f32x4*)(orow + t * 8) = y0;
  *(f32x4*)(orow + t * 8 + 4) = y1;
  *(short8*)(ob + (size_t)row * D_ + t * 8) = yb;
}

// ---------------- l2norm q,k + head reorder; v convert ----------------
__global__ __launch_bounds__(256) void k_l2norm(const float* __restrict__ q,
                                                const float* __restrict__ k,
                                                const float* __restrict__ v,
                                                u16* __restrict__ qn,
                                                u16* __restrict__ kn,
                                                u16* __restrict__ vn) {
  const int gw = blockIdx.x * 4 + (threadIdx.x >> 6);
  const int l = threadIdx.x & 63;
  const int h = gw & (H_ - 1);
  const int s = (gw >> 4) & (S_ - 1);
  const int b = gw >> 14;
  const size_t src = ((size_t)(b * S_ + s)) * D_ + h * DH_ + l * 2;
  const size_t dst = (((size_t)(b * H_ + h)) * S_ + s) * DH_ + l * 2;
  {
    f32x2 xv = *(const f32x2*)(q + src);
    float ss = xv[0] * xv[0] + xv[1] * xv[1];
#pragma unroll
    for (int off = 1; off < 64; off <<= 1) ss += __shfl_xor(ss, off);
    float sc = 1.f / (sqrtf(ss) + 1e-6f);
    u16x2 o; o[0] = f2bf(xv[0] * sc); o[1] = f2bf(xv[1] * sc);
    *(u16x2*)(qn + dst) = o;
  }
  {
    f32x2 xv = *(const f32x2*)(k + src);
    float ss = xv[0] * xv[0] + xv[1] * xv[1];
#pragma unroll
    for (int off = 1; off < 64; off <<= 1) ss += __shfl_xor(ss, off);
    float sc = 1.f / (sqrtf(ss) + 1e-6f);
    u16x2 o; o[0] = f2bf(xv[0] * sc); o[1] = f2bf(xv[1] * sc);
    *(u16x2*)(kn + dst) = o;
  }
  {
    f32x2 xv = *(const f32x2*)(v + src);
    u16x2 o; o[0] = f2bf(xv[0]); o[1] = f2bf(xv[1]);
    *(u16x2*)(vn + dst) = o;
  }
}

// ============ 256x256 8-phase GEMM (T2 swizzle + T3/T4 counted pipeline + T5) ============
// C[M,N] = A[M,K]*Bt[N,K]^T. 512 threads, 8 waves (2x4), wave tile 128x64, BK=64.
// LDS 128KB: 2 bufs x (A 256x64 + B 256x64) bf16, XOR-swizzled (byte ^= (row&7)<<4,
// write side via pre-swizzled global source -> involution both sides).
// Per K-tile: 4 phases, each = ds_read + barrier + setprio(1) 16 MFMA setprio(0) + barrier.
// Next tile's 8 gload_lds issued at phase 0 -> 3 phases of latency cover before the
// single per-tile vmcnt(0)+barrier.
// EPI 0: outf = acc + bias ; EPI 2: outb = bf16(gelu(acc+bias)) ; EPI 3: outf = acc
template <int EPI>
__device__ __forceinline__ void gemm256_core(const u16* __restrict__ A,
                                             const u16* __restrict__ Bt,
                                             const float* __restrict__ bias,
                                             float* __restrict__ outf,
                                             u16* __restrict__ outb,
                                             int N, int K, int kbase, int nk) {
  __shared__ u16 lds[2][32768];  // 2 x 64KB
  const int t = threadIdx.x;
  const int l = t & 63, w = t >> 6;
  const int wr = w >> 2, wc = w & 3;  // 2 x 4 waves
  const int l15 = l & 15, lhi = l >> 4;
  const int m0 = blockIdx.y * 256, n0 = blockIdx.x * 256;
  const int sw = (l15 & 7) << 4;  // read-side swizzle (row&7 == l15&7 for frag rows)

  // staging source offsets: thread t, issue j -> LDS linear byte p=(j*512+t)*16
  uint32_t soff[8];
#pragma unroll
  for (int j = 0; j < 8; j++) {
    const int p = (j * 512 + t) * 16;
    const int o = p & 32767;           // offset within A- or B-region
    const int row = o >> 7;            // 0..255
    const int sb = o & 127;
    const int scol = sb ^ ((row & 7) << 4);  // pre-swizzled source column bytes
    const int grow = ((p >> 15) ? n0 : m0) + row;
    soff[j] = (uint32_t)grow * (uint32_t)(K * 2) + (uint32_t)(scol + kbase * 2);
  }

  auto stage = [&](int kt, int bsel) {
    char* dst = (char*)&lds[bsel][0];
    const size_t ko = (size_t)kt * 128;  // BK=64 bf16 = 128 bytes along K
#pragma unroll
    for (int j = 0; j < 8; j++) {
      const char* src = (const char*)(j < 4 ? A : Bt) + soff[j] + ko;
      gload16(src, dst + (j * 512 + t) * 16);
    }
  };

  f32x4 acc[8][4] = {};

  stage(0, 0);
  asm volatile("s_waitcnt vmcnt(0)" ::: "memory");
  __builtin_amdgcn_sched_barrier(0);
  __builtin_amdgcn_s_barrier();

  int buf = 0;
  for (int kt = 0; kt < nk; ++kt) {
    const char* Ab = (const char*)&lds[buf][0];
    const char* Bb = Ab + 32768;
    short8 bf[4][2];
#pragma unroll
    for (int ni = 0; ni < 4; ni++)
#pragma unroll
      for (int ks = 0; ks < 2; ks++) {
        const int row = wc * 64 + ni * 16 + l15;
        bf[ni][ks] = *(const short8*)(Bb + row * 128 + ((ks * 64 + lhi * 16) ^ sw));
      }
#pragma unroll
    for (int q = 0; q < 4; q++) {
      short8 af[2][2];
#pragma unroll
      for (int mi = 0; mi < 2; mi++)
#pragma unroll
        for (int ks = 0; ks < 2; ks++) {
          const int row = wr * 128 + q * 32 + mi * 16 + l15;
          af[mi][ks] = *(const short8*)(Ab + row * 128 + ((ks * 64 + lhi * 16) ^ sw));
        }
      if (q == 0 && kt + 1 < nk) stage(kt + 1, buf ^ 1);
      __builtin_amdgcn_s_barrier();
      __builtin_amdgcn_s_setprio(1);
#pragma unroll
      for (int mi = 0; mi < 2; mi++)
#pragma unroll
        for (int ni = 0; ni < 4; ni++)
#pragma unroll
          for (int ks = 0; ks < 2; ks++)
            acc[q * 2 + mi][ni] =
                __builtin_amdgcn_mfma_f32_16x16x32_bf16(af[mi][ks], bf[ni][ks],
                                                        acc[q * 2 + mi][ni], 0, 0, 0);
      __builtin_amdgcn_s_setprio(0);
      if (q < 3) __builtin_amdgcn_s_barrier();
    }
    asm volatile("s_waitcnt vmcnt(0)" ::: "memory");
    __builtin_amdgcn_sched_barrier(0);
    __builtin_amdgcn_s_barrier();
    buf ^= 1;
  }

#pragma unroll
  for (int ni = 0; ni < 4; ni++) {
    const int col = n0 + wc * 64 + ni * 16 + l15;
    const float bcol = (EPI == 3) ? 0.f : bias[col];
#pragma unroll
    for (int mi = 0; mi < 8; mi++) {
      const int row = m0 + wr * 128 + mi * 16 + lhi * 4;
#pragma unroll
      for (int j = 0; j < 4; j++) {
        const float v = acc[mi][ni][j] + bcol;
        const size_t idx = (size_t)(row + j) * N + col;
        if (EPI == 0) outf[idx] = v;
        else if (EPI == 2) outb[idx] = f2bf(gelu_f(v));
        else outf[idx] = v;
      }
    }
  }
}

__global__ __launch_bounds__(512, 2) void k_qkv256(const u16* A, const u16* W,
                                                   const float* b0, const float* b1,
                                                   const float* b2, float* o0, float* o1,
                                                   float* o2) {
  const int z = blockIdx.z;
  const u16* Bt = W + (size_t)z * 4194304;  // WQ/WK/WV contiguous
  const float* bias = z == 0 ? b0 : (z == 1 ? b1 : b2);
  float* out = z == 0 ? o0 : (z == 1 ? o1 : o2);
  gemm256_core<0>(A, Bt, bias, out, nullptr, D_, D_, 0, 32);
}

__global__ __launch_bounds__(512, 2) void k_ffn1_256(const u16* A, const u16* Bt,
                                                     const float* bias, u16* outb) {
  gemm256_core<2>(A, Bt, bias, nullptr, outb, F_, D_, 0, 32);
}

__global__ __launch_bounds__(512, 2) void k_ffn2_256(const u16* A, const u16* Bt, float* P) {
  gemm256_core<3>(A, Bt, nullptr, P + (size_t)blockIdx.z * M_ * D_, nullptr, D_, F_,
                  blockIdx.z * 2048, 32);
}

// ---------------- 128x128 2-phase GEMM (kept for o-proj: EPI1 residual) ----------------
__device__ __forceinline__ void gemm128_res(const u16* __restrict__ A,
                                            const u16* __restrict__ Bt,
                                            const float* __restrict__ bias,
                                            const float* __restrict__ res,
                                            const float* __restrict__ alpha,
                                            float* __restrict__ outf, int N, int K) {
  __shared__ u16 As[2][128 * 32];
  __shared__ u16 Bs[2][128 * 32];
  const int t = threadIdx.x;
  const int l = t & 63;
  const int w = t >> 6;
  const int wr = w >> 1, wc = w & 1;
  const int l15 = l & 15, lhi = l >> 4;
  const int m0 = blockIdx.y * 128, n0 = blockIdx.x * 128;
  f32x4 acc[4][4] = {};
  const int srow = t >> 2;
  const int scol = (t & 3) * 8;
  const u16* Ag = A + (size_t)(m0 + srow) * K + scol;
  const u16* Ag2 = Ag + (size_t)64 * K;
  const u16* Bg = Bt + (size_t)(n0 + srow) * K + scol;
  const u16* Bg2 = Bg + (size_t)64 * K;
  const int loff = t * 16;
  const int kiters = K / 32;

  gload16(Ag, (char*)As[0] + loff);
  gload16(Ag2, (char*)As[0] + 4096 + loff);
  gload16(Bg, (char*)Bs[0] + loff);
  gload16(Bg2, (char*)Bs[0] + 4096 + loff);
  __syncthreads();

  int cur = 0;
  for (int it = 0; it < kiters; ++it) {
    if (it + 1 < kiters) {
      const int k0 = (it + 1) * 32;
      char* dA = (char*)As[cur ^ 1] + loff;
      char* dB = (char*)Bs[cur ^ 1] + loff;
      gload16(Ag + k0, dA);
      gload16(Ag2 + k0, dA + 4096);
      gload16(Bg + k0, dB);
      gload16(Bg2 + k0, dB + 4096);
    }
    short8 af[4], bfr[4];
#pragma unroll
    for (int i = 0; i < 4; i++)
      af[i] = *(const short8*)(As[cur] + (wr * 64 + i * 16 + l15) * 32 + lhi * 8);
#pragma unroll
    for (int i = 0; i < 4; i++)
      bfr[i] = *(const short8*)(Bs[cur] + (wc * 64 + i * 16 + l15) * 32 + lhi * 8);
#pragma unroll
    for (int mi = 0; mi < 4; mi++)
#pragma unroll
      for (int ni = 0; ni < 4; ni++)
        acc[mi][ni] = __builtin_amdgcn_mfma_f32_16x16x32_bf16(af[mi], bfr[ni], acc[mi][ni], 0, 0, 0);
    __syncthreads();
    cur ^= 1;
  }
#pragma unroll
  for (int ni = 0; ni < 4; ni++) {
    const int col = n0 + wc * 64 + ni * 16 + l15;
    const float bcol = bias[col];
    const float alc = clipa(alpha[col]);
#pragma unroll
    for (int mi = 0; mi < 4; mi++) {
#pragma unroll
      for (int j = 0; j < 4; j++) {
        const int row = m0 + wr * 64 + mi * 16 + lhi * 4 + j;
        const size_t idx = (size_t)row * N + col;
        outf[idx] = res[idx] + alc * (acc[mi][ni][j] + bcol);
      }
    }
  }
}

__global__ __launch_bounds__(256) void k_oproj(const u16* A, const u16* Bt, const float* bias,
                                               const float* res, const float* alpha,
                                               float* outf) {
  gemm128_res(A, Bt, bias, res, alpha, outf, D_, D_);
}

// out = res + clip(alpha)*(sum_z P[z] + bias)
__global__ __launch_bounds__(256) void k_ffn2_combine(const float* __restrict__ P,
                                                      const float* __restrict__ bias,
                                                      const float* __restrict__ res,
                                                      const float* __restrict__ alpha,
                                                      float* __restrict__ out) {
  const int i = blockIdx.x * 256 + threadIdx.x;
  const size_t base = (size_t)i * 8;
  const int col = (int)(base & (D_ - 1));
  const size_t PS = (size_t)M_ * D_;
  f32x4 s0 = {}, s1 = {};
#pragma unroll
  for (int p = 0; p < 4; p++) {
    s0 += *(const f32x4*)(P + p * PS + base);
    s1 += *(const f32x4*)(P + p * PS + base + 4);
  }
  f32x4 b0 = *(const f32x4*)(bias + col);
  f32x4 b1 = *(const f32x4*)(bias + col + 4);
  f32x4 a0 = *(const f32x4*)(alpha + col);
  f32x4 a1 = *(const f32x4*)(alpha + col + 4);
  f32x4 r0 = *(const f32x4*)(res + base);
  f32x4 r1 = *(const f32x4*)(res + base + 4);
  f32x4 o0, o1;
#pragma unroll
  for (int j = 0; j < 4; j++) {
    o0[j] = r0[j] + clipa(a0[j]) * (s0[j] + b0[j]);
    o1[j] = r1[j] + clipa(a1[j]) * (s1[j] + b1[j]);
  }
  *(f32x4*)(out + base) = o0;
  *(f32x4*)(out + base + 4) = o1;
}

// ---------------- attention: cosine attn, causal, online softmax ----------------
__global__ __launch_bounds__(256) void k_attn(const u16* __restrict__ qn,
                                              const u16* __restrict__ kn,
                                              const u16* __restrict__ vn,
                                              const float* __restrict__ tau,
                                              const float* __restrict__ nu,
                                              u16* __restrict__ o) {
  __shared__ u16 Ks[64 * 128];   // row-major [kv][dh], XOR-swizzled
  __shared__ u16 Vt[128 * 64];   // transposed [dh][kv], XOR-swizzled
  __shared__ u16 Pl[4][16][72];  // per-wave P, +8 pad
  const int t = threadIdx.x;
  const int l = t & 63, w = t >> 6;
  const int l15 = l & 15, lhi = l >> 4;
  const int qt = blockIdx.x;
  const int bh = blockIdx.y;
  const int h = bh & (H_ - 1);
  const int b = bh >> 4;
  const size_t hoff = (size_t)bh * S_ * DH_;
  const u16* Qh = qn + hoff;
  const u16* Kh = kn + hoff;
  const u16* Vh = vn + hoff;
  const int q0 = qt * 64;
  const int r0 = q0 + w * 16;
  short8 qf[4];
#pragma unroll
  for (int kk = 0; kk < 4; kk++)
    qf[kk] = *(const short8*)(Qh + (size_t)(r0 + l15) * DH_ + kk * 32 + lhi * 8);
  const float taum = tau[h];
  float mrow[4], lrow[4];
  f32x4 oacc[8] = {};
#pragma unroll
  for (int j = 0; j < 4; j++) { mrow[j] = -1e30f; lrow[j] = 0.f; }

  for (int kv0 = 0; kv0 < q0 + 64; kv0 += 64) {
#pragma unroll
    for (int i = 0; i < 4; i++) {
      const int p = i * 4096 + t * 16;
      const int row = p >> 8;
      const int colb = p & 255;
      const int scolb = colb ^ ((row & 7) << 4);
      gload16((const char*)(Kh + (size_t)(kv0 + row) * DH_) + scolb, (char*)Ks + p);
    }
#pragma unroll
    for (int i = 0; i < 4; i++) {
      const int c0 = w * 8 + i * 32;
      const int r = l;
      short8 vv = *(const short8*)(Vh + (size_t)(kv0 + r) * DH_ + c0);
#pragma unroll
      for (int j = 0; j < 8; j++) {
        const int ba = ((c0 + j) * 128 + r * 2) ^ (((c0 + j) & 7) << 4);
        *(u16*)((char*)Vt + ba) = (u16)vv[j];
      }
    }
    __syncthreads();
    f32x4 st[4] = {};
#pragma unroll
    for (int ks = 0; ks < 4; ks++) {
#pragma unroll
      for (int ct = 0; ct < 4; ct++) {
        const int n = ct * 16 + l15;
        const int ka = (ks * 32 + lhi * 8) * 2;
        short8 kf = *(const short8*)((const char*)Ks + n * 256 + (ka ^ ((n & 7) << 4)));
        st[ct] = __builtin_amdgcn_mfma_f32_16x16x32_bf16(qf[ks], kf, st[ct], 0, 0, 0);
      }
    }
    float pm[4] = {-1e30f, -1e30f, -1e30f, -1e30f};
#pragma unroll
    for (int ct = 0; ct < 4; ct++) {
      const int col = kv0 + ct * 16 + l15;
#pragma unroll
      for (int j = 0; j < 4; j++) {
        const int row = r0 + lhi * 4 + j;
        float s = st[ct][j] * taum;
        s = (col <= row) ? s : -1e30f;
        st[ct][j] = s;
        pm[j] = fmaxf(pm[j], s);
      }
    }
#pragma unroll
    for (int j = 0; j < 4; j++) {
#pragma unroll
      for (int off = 1; off < 16; off <<= 1) pm[j] = fmaxf(pm[j], __shfl_xor(pm[j], off));
    }
    float scl[4], psum[4];
#pragma unroll
    for (int j = 0; j < 4; j++) {
      const float nm = fmaxf(mrow[j], pm[j]);
      scl[j] = __expf(mrow[j] - nm);
      mrow[j] = nm;
      psum[j] = 0.f;
    }
#pragma unroll
    for (int ct = 0; ct < 4; ct++) {
#pragma unroll
      for (int j = 0; j < 4; j++) {
        const float p = __expf(st[ct][j] - mrow[j]);
        psum[j] += p;
        Pl[w][lhi * 4 + j][ct * 16 + l15] = f2bf(p);
      }
    }
#pragma unroll
    for (int j = 0; j < 4; j++) {
#pragma unroll
      for (int off = 1; off < 16; off <<= 1) psum[j] += __shfl_xor(psum[j], off);
      lrow[j] = lrow[j] * scl[j] + psum[j];
    }
#pragma unroll
    for (int nt = 0; nt < 8; nt++) {
#pragma unroll
      for (int j = 0; j < 4; j++) oacc[nt][j] *= scl[j];
    }
#pragma unroll
    for (int ks2 = 0; ks2 < 2; ks2++) {
      short8 pa = *(const short8*)((const char*)&Pl[w][0][0] + l15 * 144 + ks2 * 64 + lhi * 16);
#pragma unroll
      for (int nt = 0; nt < 8; nt++) {
        const int n = nt * 16 + l15;
        const int ba = (n * 128 + (ks2 * 32 + lhi * 8) * 2) ^ ((n & 7) << 4);
        short8 vf = *(const short8*)((const char*)Vt + ba);
        oacc[nt] = __builtin_amdgcn_mfma_f32_16x16x32_bf16(pa, vf, oacc[nt], 0, 0, 0);
      }
    }
    __syncthreads();
  }
  const float num = nu[h];
  float rs[4];
#pragma unroll
  for (int j = 0; j < 4; j++) rs[j] = num / lrow[j];
#pragma unroll
  for (int nt = 0; nt < 8; nt++) {
    const int col = h * DH_ + nt * 16 + l15;
#pragma unroll
    for (int j = 0; j < 4; j++) {
      const int row = r0 + lhi * 4 + j;
      o[((size_t)b * S_ + row) * D_ + col] = f2bf(oacc[nt][j] * rs[j]);
    }
  }
}

// ---------------- launch ----------------
extern "C" void kernel_launch(void* const* d_in, const int* in_sizes, int n_in,
                              void* d_out, int out_size, void* d_ws, size_t ws_size,
                              hipStream_t stream) {
  const float* x    = (const float*)d_in[0];
  const float* ln1g = (const float*)d_in[1];
  const float* ln1b = (const float*)d_in[2];
  const float* wq   = (const float*)d_in[3];
  const float* bq   = (const float*)d_in[4];
  const float* wk   = (const float*)d_in[5];
  const float* bk   = (const float*)d_in[6];
  const float* wv   = (const float*)d_in[7];
  const float* bv   = (const float*)d_in[8];
  const float* wo   = (const float*)d_in[9];
  const float* bo   = (const float*)d_in[10];
  const float* tau  = (const float*)d_in[11];
  const float* nu   = (const float*)d_in[12];
  const float* al1  = (const float*)d_in[13];
  const float* ln2g = (const float*)d_in[14];
  const float* ln2b = (const float*)d_in[15];
  const float* w1   = (const float*)d_in[16];
  const float* b1   = (const float*)d_in[17];
  const float* w2   = (const float*)d_in[18];
  const float* b2   = (const float*)d_in[19];
  const float* al2  = (const float*)d_in[20];

  char* ws = (char*)d_ws;
  u16* WQ = (u16*)(ws + 0);
  u16* WK = (u16*)(ws + 8388608);
  u16* WV = (u16*)(ws + 16777216);
  u16* WO = (u16*)(ws + 25165824);
  u16* W1B = (u16*)(ws + 33554432);
  u16* W2B = (u16*)(ws + 67108864);
  float* AF = (float*)(ws + 100663296);   // centernorm1 f32
  u16*   AB = (u16*)(ws + 117440512);     // centernorm1 bf16
  float* QF = (float*)(ws + 125829120);
  float* KF = (float*)(ws + 142606336);
  float* VF = (float*)(ws + 159383552);
  u16* QN = (u16*)(ws + 176160768);
  u16* KN = (u16*)(ws + 184549376);
  u16* VN = (u16*)(ws + 192937984);
  // reuse after l2norm / attention:
  u16*   OB = (u16*)(ws + 125829120);     // attn out bf16 (over QF)
  u16*   MB = (u16*)(ws + 134217728);     // centernorm2 bf16 (over QF hi half)
  float* X1 = (float*)(ws + 142606336);   // residual1 f32 (over KF)
  float* MF = (float*)(ws + 159383552);   // centernorm2 f32 (over VF)
  u16*   HB = (u16*)(ws + 176160768);     // ffn hidden bf16 (over QN..)
  float* P4 = (float*)(ws + 0);           // ffn2 split-K partials, 4x16MB (over dead WQ..W1B)

  // weights -> bf16
  k_cvt<<<2048, 256, 0, stream>>>(wq, WQ, 524288);
  k_cvt<<<2048, 256, 0, stream>>>(wk, WK, 524288);
  k_cvt<<<2048, 256, 0, stream>>>(wv, WV, 524288);
  k_cvt<<<2048, 256, 0, stream>>>(wo, WO, 524288);
  k_cvt<<<8192, 256, 0, stream>>>(w1, W1B, 2097152);
  k_cvt<<<8192, 256, 0, stream>>>(w2, W2B, 2097152);

  // centernorm 1
  k_centernorm<<<M_, 256, 0, stream>>>(x, ln1g, ln1b, AF, AB);

  // qkv projections (256^2 8-phase; WQ/WK/WV contiguous)
  k_qkv256<<<dim3(8, 8, 3), 512, 0, stream>>>(AB, WQ, bq, bk, bv, QF, KF, VF);

  // l2norm + head reorder
  k_l2norm<<<8192, 256, 0, stream>>>(QF, KF, VF, QN, KN, VN);

  // attention
  k_attn<<<dim3(S_ / 64, B_ * H_), 256, 0, stream>>>(QN, KN, VN, tau, nu, OB);

  // output projection + residual (x1 = a + a1*attn) — 128^2 path (grid richness)
  k_oproj<<<dim3(16, 16), 256, 0, stream>>>(OB, WO, bo, AF, al1, X1);

  // centernorm 2
  k_centernorm<<<M_, 256, 0, stream>>>(X1, ln2g, ln2b, MF, MB);

  // ffn1 (gelu -> bf16)
  k_ffn1_256<<<dim3(32, 8), 512, 0, stream>>>(MB, W1B, b1, HB);

  // ffn2 split-K=4 partials + combine (out = m + a2*(sum+bias))
  k_ffn2_256<<<dim3(8, 8, 4), 512, 0, stream>>>(HB, W2B, P4);
  k_ffn2_combine<<<2048, 256, 0, stream>>>(P4, b2, MF, al2, (float*)d_out);
}

// Round 4
// 407.916 us; speedup vs baseline: 1.3680x; 1.0369x over previous
//
#include <hip/hip_runtime.h>
#include <hip/hip_bf16.h>
#include <stdint.h>

#define B_ 2
#define S_ 1024
#define D_ 2048
#define H_ 16
#define F_ 8192
#define DH_ 128
#define M_ 2048  // B*S

typedef unsigned short u16;
typedef __attribute__((ext_vector_type(8))) short short8;
typedef __attribute__((ext_vector_type(4))) float f32x4;
typedef __attribute__((ext_vector_type(2))) float f32x2;
typedef __attribute__((ext_vector_type(2))) unsigned short u16x2;

__device__ __forceinline__ u16 f2bf(float f) {
  union { float f; uint32_t u; } c; c.f = f;
  uint32_t r = c.u + 0x7FFFu + ((c.u >> 16) & 1u);
  return (u16)(r >> 16);
}

__device__ __forceinline__ void gload16(const void* g, void* l) {
  __builtin_amdgcn_global_load_lds((const __attribute__((address_space(1))) void*)g,
                                   (__attribute__((address_space(3))) void*)l, 16, 0, 0);
}

__device__ __forceinline__ float clipa(float a) {
  return fminf(0.2f, fmaxf(-0.2f, a));
}

__device__ __forceinline__ float gelu_f(float x) {
  float z = 0.7978845608028654f * (x + 0.044715f * x * x * x);
  z = fminf(10.f, fmaxf(-10.f, z));
  float e = __expf(2.f * z);
  return 0.5f * x * (1.f + (e - 1.f) / (e + 1.f));
}

// ---------------- f32 -> bf16 vector convert ----------------
__global__ __launch_bounds__(256) void k_cvt(const float* __restrict__ s,
                                             u16* __restrict__ d, int n8) {
  int i = blockIdx.x * 256 + threadIdx.x;
  if (i >= n8) return;
  f32x4 a = *(const f32x4*)(s + (size_t)i * 8);
  f32x4 b = *(const f32x4*)(s + (size_t)i * 8 + 4);
  short8 o;
  o[0] = (short)f2bf(a[0]); o[1] = (short)f2bf(a[1]);
  o[2] = (short)f2bf(a[2]); o[3] = (short)f2bf(a[3]);
  o[4] = (short)f2bf(b[0]); o[5] = (short)f2bf(b[1]);
  o[6] = (short)f2bf(b[2]); o[7] = (short)f2bf(b[3]);
  *(short8*)(d + (size_t)i * 8) = o;
}

// ---------------- CenterNorm ----------------
__global__ __launch_bounds__(256) void k_centernorm(const float* __restrict__ x,
                                                    const float* __restrict__ g,
                                                    const float* __restrict__ bb,
                                                    float* __restrict__ of,
                                                    u16* __restrict__ ob) {
  const int row = blockIdx.x;
  const int t = threadIdx.x;
  const float* xr = x + (size_t)row * D_;
  f32x4 v0 = *(const f32x4*)(xr + t * 8);
  f32x4 v1 = *(const f32x4*)(xr + t * 8 + 4);
  float s = v0[0] + v0[1] + v0[2] + v0[3] + v1[0] + v1[1] + v1[2] + v1[3];
#pragma unroll
  for (int off = 1; off < 64; off <<= 1) s += __shfl_xor(s, off);
  __shared__ float red[4];
  if ((t & 63) == 0) red[t >> 6] = s;
  __syncthreads();
  const float mu = (red[0] + red[1] + red[2] + red[3]) * (1.0f / D_);
  const float CNS = (float)D_ / (float)(D_ - 1);
  f32x4 g0 = *(const f32x4*)(g + t * 8);
  f32x4 g1 = *(const f32x4*)(g + t * 8 + 4);
  f32x4 b0 = *(const f32x4*)(bb + t * 8);
  f32x4 b1 = *(const f32x4*)(bb + t * 8 + 4);
  f32x4 y0, y1;
  short8 yb;
#pragma unroll
  for (int i = 0; i < 4; i++) {
    y0[i] = g0[i] * (CNS * (v0[i] - mu)) + b0[i];
    y1[i] = g1[i] * (CNS * (v1[i] - mu)) + b1[i];
  }
#pragma unroll
  for (int i = 0; i < 4; i++) { yb[i] = (short)f2bf(y0[i]); yb[4 + i] = (short)f2bf(y1[i]); }
  float* orow = of + (size_t)row * D_;
  *(f32x4*)(orow + t * 8) = y0;
  *(f32x4*)(orow + t * 8 + 4) = y1;
  *(short8*)(ob + (size_t)row * D_ + t * 8) = yb;
}

// ---------------- l2norm q,k + head reorder; v convert ----------------
__global__ __launch_bounds__(256) void k_l2norm(const float* __restrict__ q,
                                                const float* __restrict__ k,
                                                const float* __restrict__ v,
                                                u16* __restrict__ qn,
                                                u16* __restrict__ kn,
                                                u16* __restrict__ vn) {
  const int gw = blockIdx.x * 4 + (threadIdx.x >> 6);
  const int l = threadIdx.x & 63;
  const int h = gw & (H_ - 1);
  const int s = (gw >> 4) & (S_ - 1);
  const int b = gw >> 14;
  const size_t src = ((size_t)(b * S_ + s)) * D_ + h * DH_ + l * 2;
  const size_t dst = (((size_t)(b * H_ + h)) * S_ + s) * DH_ + l * 2;
  {
    f32x2 xv = *(const f32x2*)(q + src);
    float ss = xv[0] * xv[0] + xv[1] * xv[1];
#pragma unroll
    for (int off = 1; off < 64; off <<= 1) ss += __shfl_xor(ss, off);
    float sc = 1.f / (sqrtf(ss) + 1e-6f);
    u16x2 o; o[0] = f2bf(xv[0] * sc); o[1] = f2bf(xv[1] * sc);
    *(u16x2*)(qn + dst) = o;
  }
  {
    f32x2 xv = *(const f32x2*)(k + src);
    float ss = xv[0] * xv[0] + xv[1] * xv[1];
#pragma unroll
    for (int off = 1; off < 64; off <<= 1) ss += __shfl_xor(ss, off);
    float sc = 1.f / (sqrtf(ss) + 1e-6f);
    u16x2 o; o[0] = f2bf(xv[0] * sc); o[1] = f2bf(xv[1] * sc);
    *(u16x2*)(kn + dst) = o;
  }
  {
    f32x2 xv = *(const f32x2*)(v + src);
    u16x2 o; o[0] = f2bf(xv[0]); o[1] = f2bf(xv[1]);
    *(u16x2*)(vn + dst) = o;
  }
}

// ============ ring-4 counted-vmcnt GEMM (T1+T2-by-permutation+T4+T5) ============
// C[M,N] = A[M,K]*Bt[N,K]^T. BK=32, 4 LDS ring slots, staging 3 tiles ahead,
// per-tile wait = vmcnt(8) (8 loads stay in flight across the barrier).
// LDS layout is a 16B-unit permutation chosen so each wave's fragment reads are
// 64 consecutive 16B units (stride-1, conflict-free); the matching inverse
// permutation is applied to the per-lane GLOBAL source address (gload_lds writes
// linearly: rule #21 both-sides-or-neither).
// unit u (within A or B region) = block*64 + r16*4 + lhi  <->  row=block*16+r16,
// kbytes=lhi*16.  Requires nk >= 3.
// EPI 0: outf=acc+bias ; 1: outf=res+clip(alpha)*(acc+bias) ; 2: outb=bf16(gelu) ; 3: raw
template <int WM, int WN, int MF, int EPI>
__device__ __forceinline__ void gemm_ring(const u16* __restrict__ A,
                                          const u16* __restrict__ Bt,
                                          const float* __restrict__ bias,
                                          const float* __restrict__ res,
                                          const float* __restrict__ alpha,
                                          float* __restrict__ outf,
                                          u16* __restrict__ outb,
                                          int N, int K, int kbase, int nk,
                                          int m0, int n0) {
  constexpr int NT = WM * WN * 64;     // threads
  constexpr int BM = NT / 2;           // rows of A tile (= WM*MF*16)
  constexpr int BN = WN * 64;          // cols of C tile
  constexpr int RING = (BM + BN) * 64; // bytes per ring slot (BK=32 bf16 = 64B/row)
  __shared__ char lds[4][RING];
  const int t = threadIdx.x;
  const int l = t & 63, w = t >> 6;
  const int wr = w / WN, wc = w % WN;
  const int l15 = l & 15, lhi = l >> 4;
  const int rp16 = (((l & 15) << 2) | (l >> 4)) * 16;  // lane -> unit-in-block

  // per-lane global source offsets (inverse of the LDS unit permutation)
  size_t soff[4];
#pragma unroll
  for (int j = 0; j < 4; j++) {
    const int v = j * NT + t;            // linear 16B unit this lane writes
    const int u = v & (2 * NT - 1);      // unit within A or B region
    const int row = ((u >> 6) << 4) | ((u >> 2) & 15);
    const int lh = u & 3;
    const int grow = (j >= 2 ? n0 : m0) + row;
    soff[j] = (size_t)grow * (size_t)(K * 2) + (size_t)(kbase * 2 + lh * 16);
  }

  auto stage = [&](int kt) {
    char* dst = &lds[kt & 3][0] + t * 16;
    const size_t ko = (size_t)kt * 64;
#pragma unroll
    for (int j = 0; j < 4; j++) {
      const char* src = (const char*)(j >= 2 ? Bt : A) + soff[j] + ko;
      gload16(src, dst + j * NT * 16);
    }
  };

  f32x4 acc[MF][4] = {};

  stage(0); stage(1); stage(2);
  asm volatile("s_waitcnt vmcnt(8)" ::: "memory");
  __builtin_amdgcn_s_barrier();
  __builtin_amdgcn_sched_barrier(0);

  for (int kt = 0; kt < nk; ++kt) {
    const char* Ab = &lds[kt & 3][0];
    const char* Bb = Ab + BM * 64;
    short8 bf[4], af[MF];
#pragma unroll
    for (int ni = 0; ni < 4; ni++)
      bf[ni] = *(const short8*)(Bb + (wc * 4 + ni) * 1024 + rp16);
#pragma unroll
    for (int mi = 0; mi < MF; mi++)
      af[mi] = *(const short8*)(Ab + (wr * MF + mi) * 1024 + rp16);
    if (kt + 3 < nk) stage(kt + 3);
    __builtin_amdgcn_s_setprio(1);
#pragma unroll
    for (int mi = 0; mi < MF; mi++)
#pragma unroll
      for (int ni = 0; ni < 4; ni++)
        acc[mi][ni] = __builtin_amdgcn_mfma_f32_16x16x32_bf16(af[mi], bf[ni], acc[mi][ni], 0, 0, 0);
    __builtin_amdgcn_s_setprio(0);
    if (kt + 1 < nk) {
      if (kt + 3 < nk)      asm volatile("s_waitcnt vmcnt(8)" ::: "memory");
      else if (kt + 2 < nk) asm volatile("s_waitcnt vmcnt(4)" ::: "memory");
      else                  asm volatile("s_waitcnt vmcnt(0)" ::: "memory");
      __builtin_amdgcn_s_barrier();
      __builtin_amdgcn_sched_barrier(0);
    }
  }

#pragma unroll
  for (int ni = 0; ni < 4; ni++) {
    const int col = n0 + wc * 64 + ni * 16 + l15;
    const float bcol = (EPI == 3) ? 0.f : bias[col];
    float alc = 0.f;
    if (EPI == 1) alc = clipa(alpha[col]);
#pragma unroll
    for (int mi = 0; mi < MF; mi++) {
      const int row = m0 + wr * MF * 16 + mi * 16 + lhi * 4;
#pragma unroll
      for (int j = 0; j < 4; j++) {
        const float v = acc[mi][ni][j] + bcol;
        const size_t idx = (size_t)(row + j) * N + col;
        if (EPI == 0) outf[idx] = v;
        else if (EPI == 1) outf[idx] = res[idx] + alc * v;
        else if (EPI == 2) outb[idx] = f2bf(gelu_f(v));
        else outf[idx] = v;
      }
    }
  }
}

// XCD-aware swizzle of the 2D (x,y) grid; nwg must be %8==0 (all ours are)
__device__ __forceinline__ void xcd_swz(int gx, int gy, int& bx, int& by) {
  const int nwg = gx * gy;
  const int bid = blockIdx.y * gx + blockIdx.x;
  const int s = (bid & 7) * (nwg >> 3) + (bid >> 3);
  bx = s % gx;
  by = s / gx;
}

__global__ __launch_bounds__(512, 2) void k_qkv256(const u16* A, const u16* W,
                                                   const float* b0, const float* b1,
                                                   const float* b2, float* o0, float* o1,
                                                   float* o2) {
  const int z = blockIdx.z;
  const u16* Bt = W + (size_t)z * 4194304;
  const float* bias = z == 0 ? b0 : (z == 1 ? b1 : b2);
  float* out = z == 0 ? o0 : (z == 1 ? o1 : o2);
  int bx, by; xcd_swz(8, 8, bx, by);
  gemm_ring<2, 4, 8, 0>(A, Bt, bias, nullptr, nullptr, out, nullptr, D_, D_, 0, 64,
                        by * 256, bx * 256);
}

__global__ __launch_bounds__(512, 2) void k_ffn1_256(const u16* A, const u16* Bt,
                                                     const float* bias, u16* outb) {
  int bx, by; xcd_swz(32, 8, bx, by);
  gemm_ring<2, 4, 8, 2>(A, Bt, bias, nullptr, nullptr, nullptr, outb, F_, D_, 0, 64,
                        by * 256, bx * 256);
}

__global__ __launch_bounds__(512, 2) void k_ffn2_256(const u16* A, const u16* Bt, float* P) {
  int bx, by; xcd_swz(8, 8, bx, by);
  gemm_ring<2, 4, 8, 3>(A, Bt, nullptr, nullptr, nullptr,
                        P + (size_t)blockIdx.z * M_ * D_, nullptr, D_, F_,
                        blockIdx.z * 2048, 64, by * 256, bx * 256);
}

__global__ __launch_bounds__(256, 2) void k_oproj(const u16* A, const u16* Bt,
                                                  const float* bias, const float* res,
                                                  const float* alpha, float* outf) {
  int bx, by; xcd_swz(16, 16, bx, by);
  gemm_ring<2, 2, 4, 1>(A, Bt, bias, res, alpha, outf, nullptr, D_, D_, 0, 64,
                        by * 128, bx * 128);
}

// out = res + clip(alpha)*(sum_z P[z] + bias)
__global__ __launch_bounds__(256) void k_ffn2_combine(const float* __restrict__ P,
                                                      const float* __restrict__ bias,
                                                      const float* __restrict__ res,
                                                      const float* __restrict__ alpha,
                                                      float* __restrict__ out) {
  const int i = blockIdx.x * 256 + threadIdx.x;
  const size_t base = (size_t)i * 8;
  const int col = (int)(base & (D_ - 1));
  const size_t PS = (size_t)M_ * D_;
  f32x4 s0 = {}, s1 = {};
#pragma unroll
  for (int p = 0; p < 4; p++) {
    s0 += *(const f32x4*)(P + p * PS + base);
    s1 += *(const f32x4*)(P + p * PS + base + 4);
  }
  f32x4 b0 = *(const f32x4*)(bias + col);
  f32x4 b1 = *(const f32x4*)(bias + col + 4);
  f32x4 a0 = *(const f32x4*)(alpha + col);
  f32x4 a1 = *(const f32x4*)(alpha + col + 4);
  f32x4 r0 = *(const f32x4*)(res + base);
  f32x4 r1 = *(const f32x4*)(res + base + 4);
  f32x4 o0, o1;
#pragma unroll
  for (int j = 0; j < 4; j++) {
    o0[j] = r0[j] + clipa(a0[j]) * (s0[j] + b0[j]);
    o1[j] = r1[j] + clipa(a1[j]) * (s1[j] + b1[j]);
  }
  *(f32x4*)(out + base) = o0;
  *(f32x4*)(out + base + 4) = o1;
}

// ---------------- attention: cosine attn, causal, online softmax ----------------
__global__ __launch_bounds__(256) void k_attn(const u16* __restrict__ qn,
                                              const u16* __restrict__ kn,
                                              const u16* __restrict__ vn,
                                              const float* __restrict__ tau,
                                              const float* __restrict__ nu,
                                              u16* __restrict__ o) {
  __shared__ u16 Ks[64 * 128];   // row-major [kv][dh], XOR-swizzled
  __shared__ u16 Vt[128 * 64];   // transposed [dh][kv], XOR-swizzled
  __shared__ u16 Pl[4][16][72];  // per-wave P, +8 pad
  const int t = threadIdx.x;
  const int l = t & 63, w = t >> 6;
  const int l15 = l & 15, lhi = l >> 4;
  const int qt = blockIdx.x;
  const int bh = blockIdx.y;
  const int h = bh & (H_ - 1);
  const int b = bh >> 4;
  const size_t hoff = (size_t)bh * S_ * DH_;
  const u16* Qh = qn + hoff;
  const u16* Kh = kn + hoff;
  const u16* Vh = vn + hoff;
  const int q0 = qt * 64;
  const int r0 = q0 + w * 16;
  short8 qf[4];
#pragma unroll
  for (int kk = 0; kk < 4; kk++)
    qf[kk] = *(const short8*)(Qh + (size_t)(r0 + l15) * DH_ + kk * 32 + lhi * 8);
  const float taum = tau[h];
  float mrow[4], lrow[4];
  f32x4 oacc[8] = {};
#pragma unroll
  for (int j = 0; j < 4; j++) { mrow[j] = -1e30f; lrow[j] = 0.f; }

  for (int kv0 = 0; kv0 < q0 + 64; kv0 += 64) {
#pragma unroll
    for (int i = 0; i < 4; i++) {
      const int p = i * 4096 + t * 16;
      const int row = p >> 8;
      const int colb = p & 255;
      const int scolb = colb ^ ((row & 7) << 4);
      gload16((const char*)(Kh + (size_t)(kv0 + row) * DH_) + scolb, (char*)Ks + p);
    }
#pragma unroll
    for (int i = 0; i < 4; i++) {
      const int c0 = w * 8 + i * 32;
      const int r = l;
      short8 vv = *(const short8*)(Vh + (size_t)(kv0 + r) * DH_ + c0);
#pragma unroll
      for (int j = 0; j < 8; j++) {
        const int ba = ((c0 + j) * 128 + r * 2) ^ (((c0 + j) & 7) << 4);
        *(u16*)((char*)Vt + ba) = (u16)vv[j];
      }
    }
    __syncthreads();
    f32x4 st[4] = {};
#pragma unroll
    for (int ks = 0; ks < 4; ks++) {
#pragma unroll
      for (int ct = 0; ct < 4; ct++) {
        const int n = ct * 16 + l15;
        const int ka = (ks * 32 + lhi * 8) * 2;
        short8 kf = *(const short8*)((const char*)Ks + n * 256 + (ka ^ ((n & 7) << 4)));
        st[ct] = __builtin_amdgcn_mfma_f32_16x16x32_bf16(qf[ks], kf, st[ct], 0, 0, 0);
      }
    }
    float pm[4] = {-1e30f, -1e30f, -1e30f, -1e30f};
#pragma unroll
    for (int ct = 0; ct < 4; ct++) {
      const int col = kv0 + ct * 16 + l15;
#pragma unroll
      for (int j = 0; j < 4; j++) {
        const int row = r0 + lhi * 4 + j;
        float s = st[ct][j] * taum;
        s = (col <= row) ? s : -1e30f;
        st[ct][j] = s;
        pm[j] = fmaxf(pm[j], s);
      }
    }
#pragma unroll
    for (int j = 0; j < 4; j++) {
#pragma unroll
      for (int off = 1; off < 16; off <<= 1) pm[j] = fmaxf(pm[j], __shfl_xor(pm[j], off));
    }
    float scl[4], psum[4];
#pragma unroll
    for (int j = 0; j < 4; j++) {
      const float nm = fmaxf(mrow[j], pm[j]);
      scl[j] = __expf(mrow[j] - nm);
      mrow[j] = nm;
      psum[j] = 0.f;
    }
#pragma unroll
    for (int ct = 0; ct < 4; ct++) {
#pragma unroll
      for (int j = 0; j < 4; j++) {
        const float p = __expf(st[ct][j] - mrow[j]);
        psum[j] += p;
        Pl[w][lhi * 4 + j][ct * 16 + l15] = f2bf(p);
      }
    }
#pragma unroll
    for (int j = 0; j < 4; j++) {
#pragma unroll
      for (int off = 1; off < 16; off <<= 1) psum[j] += __shfl_xor(psum[j], off);
      lrow[j] = lrow[j] * scl[j] + psum[j];
    }
#pragma unroll
    for (int nt = 0; nt < 8; nt++) {
#pragma unroll
      for (int j = 0; j < 4; j++) oacc[nt][j] *= scl[j];
    }
#pragma unroll
    for (int ks2 = 0; ks2 < 2; ks2++) {
      short8 pa = *(const short8*)((const char*)&Pl[w][0][0] + l15 * 144 + ks2 * 64 + lhi * 16);
#pragma unroll
      for (int nt = 0; nt < 8; nt++) {
        const int n = nt * 16 + l15;
        const int ba = (n * 128 + (ks2 * 32 + lhi * 8) * 2) ^ ((n & 7) << 4);
        short8 vf = *(const short8*)((const char*)Vt + ba);
        oacc[nt] = __builtin_amdgcn_mfma_f32_16x16x32_bf16(pa, vf, oacc[nt], 0, 0, 0);
      }
    }
    __syncthreads();
  }
  const float num = nu[h];
  float rs[4];
#pragma unroll
  for (int j = 0; j < 4; j++) rs[j] = num / lrow[j];
#pragma unroll
  for (int nt = 0; nt < 8; nt++) {
    const int col = h * DH_ + nt * 16 + l15;
#pragma unroll
    for (int j = 0; j < 4; j++) {
      const int row = r0 + lhi * 4 + j;
      o[((size_t)b * S_ + row) * D_ + col] = f2bf(oacc[nt][j] * rs[j]);
    }
  }
}

// ---------------- launch ----------------
extern "C" void kernel_launch(void* const* d_in, const int* in_sizes, int n_in,
                              void* d_out, int out_size, void* d_ws, size_t ws_size,
                              hipStream_t stream) {
  const float* x    = (const float*)d_in[0];
  const float* ln1g = (const float*)d_in[1];
  const float* ln1b = (const float*)d_in[2];
  const float* wq   = (const float*)d_in[3];
  const float* bq   = (const float*)d_in[4];
  const float* wk   = (const float*)d_in[5];
  const float* bk   = (const float*)d_in[6];
  const float* wv   = (const float*)d_in[7];
  const float* bv   = (const float*)d_in[8];
  const float* wo   = (const float*)d_in[9];
  const float* bo   = (const float*)d_in[10];
  const float* tau  = (const float*)d_in[11];
  const float* nu   = (const float*)d_in[12];
  const float* al1  = (const float*)d_in[13];
  const float* ln2g = (const float*)d_in[14];
  const float* ln2b = (const float*)d_in[15];
  const float* w1   = (const float*)d_in[16];
  const float* b1   = (const float*)d_in[17];
  const float* w2   = (const float*)d_in[18];
  const float* b2   = (const float*)d_in[19];
  const float* al2  = (const float*)d_in[20];

  char* ws = (char*)d_ws;
  u16* WQ = (u16*)(ws + 0);
  u16* WK = (u16*)(ws + 8388608);
  u16* WV = (u16*)(ws + 16777216);
  u16* WO = (u16*)(ws + 25165824);
  u16* W1B = (u16*)(ws + 33554432);
  u16* W2B = (u16*)(ws + 67108864);
  float* AF = (float*)(ws + 100663296);   // centernorm1 f32
  u16*   AB = (u16*)(ws + 117440512);     // centernorm1 bf16
  float* QF = (float*)(ws + 125829120);
  float* KF = (float*)(ws + 142606336);
  float* VF = (float*)(ws + 159383552);
  u16* QN = (u16*)(ws + 176160768);
  u16* KN = (u16*)(ws + 184549376);
  u16* VN = (u16*)(ws + 192937984);
  // reuse after l2norm / attention:
  u16*   OB = (u16*)(ws + 125829120);     // attn out bf16 (over QF)
  u16*   MB = (u16*)(ws + 134217728);     // centernorm2 bf16 (over QF hi half)
  float* X1 = (float*)(ws + 142606336);   // residual1 f32 (over KF)
  float* MF2 = (float*)(ws + 159383552);  // centernorm2 f32 (over VF)
  u16*   HB = (u16*)(ws + 176160768);     // ffn hidden bf16 (over QN..)
  float* P4 = (float*)(ws + 0);           // ffn2 split-K partials, 4x16MB (over dead WQ..W1B)

  // weights -> bf16
  k_cvt<<<2048, 256, 0, stream>>>(wq, WQ, 524288);
  k_cvt<<<2048, 256, 0, stream>>>(wk, WK, 524288);
  k_cvt<<<2048, 256, 0, stream>>>(wv, WV, 524288);
  k_cvt<<<2048, 256, 0, stream>>>(wo, WO, 524288);
  k_cvt<<<8192, 256, 0, stream>>>(w1, W1B, 2097152);
  k_cvt<<<8192, 256, 0, stream>>>(w2, W2B, 2097152);

  // centernorm 1
  k_centernorm<<<M_, 256, 0, stream>>>(x, ln1g, ln1b, AF, AB);

  // qkv projections (ring-4; WQ/WK/WV contiguous)
  k_qkv256<<<dim3(8, 8, 3), 512, 0, stream>>>(AB, WQ, bq, bk, bv, QF, KF, VF);

  // l2norm + head reorder
  k_l2norm<<<8192, 256, 0, stream>>>(QF, KF, VF, QN, KN, VN);

  // attention
  k_attn<<<dim3(S_ / 64, B_ * H_), 256, 0, stream>>>(QN, KN, VN, tau, nu, OB);

  // output projection + residual (x1 = a + a1*attn) — 128^2 ring-4
  k_oproj<<<dim3(16, 16), 256, 0, stream>>>(OB, WO, bo, AF, al1, X1);

  // centernorm 2
  k_centernorm<<<M_, 256, 0, stream>>>(X1, ln2g, ln2b, MF2, MB);

  // ffn1 (gelu -> bf16)
  k_ffn1_256<<<dim3(32, 8), 512, 0, stream>>>(MB, W1B, b1, HB);

  // ffn2 split-K=4 partials + combine (out = m + a2*(sum+bias))
  k_ffn2_256<<<dim3(8, 8, 4), 512, 0, stream>>>(HB, W2B, P4);
  k_ffn2_combine<<<2048, 256, 0, stream>>>(P4, b2, MF2, al2, (float*)d_out);
}